// Round 17
// baseline (15449.387 us; speedup 1.0000x reference)
//
#include <hip/hip_runtime.h>

#define Bn 64
#define Sn 256
#define Tn 128
#define Hn 1024
#define En 512
#define H2n 2048
#define NBLK 256
#define NTHR 1024

// rotation depths (reuse distance > fence period 8 + read window)
#define WCTX 10
#define WH 12

// LDS byte offsets (dynamic shared) -- ehb8 slice resident, weights streamed
#define EHL 0              // 131072 B: this block's ehb8 slice, [k][tid*16] layout
#define SCR 131072         // 8192 B: phA w_s+q_s / gate_c scr [4][64][8]
#define SCR2 139264        // 4096 B: pre_d [2][64][8]
#define PREP 143360        // 2048 B: pre_c [64][8]
#define GIL 145408         // 6144 B: gi [3][64][8]  (R16 bug: was budgeted 3072)
#define LDS_BYTES 151552

typedef __attribute__((ext_vector_type(8))) short short8v;
typedef __attribute__((ext_vector_type(4))) float floatx4;
typedef __attribute__((ext_vector_type(2))) float floatx2;

// HW OCP-fp8 decode if available (gfx940+/gfx950); else verified software path.
#if defined(__has_builtin)
#if __has_builtin(__builtin_amdgcn_cvt_pk_f32_fp8)
#define HW_FP8 1
#endif
#endif

__device__ __forceinline__ unsigned short f2bf(float f) {
  union { float f; unsigned u; } x; x.f = f;
  unsigned r = x.u + 0x7fffu + ((x.u >> 16) & 1u);
  return (unsigned short)(r >> 16);
}
__device__ __forceinline__ float bf2f(unsigned short u) {
  union { unsigned u; float f; } x; x.u = ((unsigned)u) << 16; return x.f;
}
__device__ __forceinline__ float sigm(float x) { return 1.f / (1.f + __expf(-x)); }
__device__ __forceinline__ float tanh_f(float x) {
  float e = __expf(2.f * x);
  return 1.f - 2.f / (e + 1.f);
}
__device__ __forceinline__ short8v ldf(const unsigned short* p) { return *(const short8v*)p; }
#define MFMA(a, b, c) __builtin_amdgcn_mfma_f32_16x16x32_bf16(a, b, c, 0, 0, 0)

// ---- fp8 e4m3fn FTZ codec (R11/R12/R15-verified in production) ----
__device__ __forceinline__ unsigned char f2fp8z(float f) {
  union { float f; unsigned u; } x; x.f = f;
  unsigned s = (x.u >> 24) & 0x80u;
  unsigned au = x.u & 0x7fffffffu;
  if (au >= 0x43e00000u) return (unsigned char)(s | 0x7Eu);   // clamp to 448
  if (au < 0x3c000000u) return (unsigned char)s;              // FTZ below 2^-7
  if (au < 0x3c800000u) return (unsigned char)(s | 0x08u);    // round to min normal
  unsigned r = au + 0x7ffffu + ((au >> 20) & 1u);             // RNE at bit 20
  unsigned e8 = ((r >> 23) & 0xffu) - 120u;
  unsigned m8 = (r >> 20) & 7u;
  return (unsigned char)(s | (e8 << 3) | m8);
}
__device__ __forceinline__ float dec1(unsigned b) {
  union { unsigned u; float f; } x;
  x.u = ((b & 0x80u) << 24) | ((b & 0x7fu) << 20);
  return x.f * 0x1p120f;
}
__device__ __forceinline__ floatx2 dec2lo(unsigned w) {
#ifdef HW_FP8
  return __builtin_amdgcn_cvt_pk_f32_fp8(w, false);
#else
  floatx2 r; r[0] = dec1(w & 0xffu); r[1] = dec1((w >> 8) & 0xffu); return r;
#endif
}
__device__ __forceinline__ floatx2 dec2hi(unsigned w) {
#ifdef HW_FP8
  return __builtin_amdgcn_cvt_pk_f32_fp8(w, true);
#else
  floatx2 r; r[0] = dec1((w >> 16) & 0xffu); r[1] = dec1(w >> 24); return r;
#endif
}
__device__ __forceinline__ void dec4f(unsigned w4, float wf, float* acc) {
  floatx2 lo = dec2lo(w4), hi = dec2hi(w4);
  acc[0] += wf * lo[0];
  acc[1] += wf * lo[1];
  acc[2] += wf * hi[0];
  acc[3] += wf * hi[1];
}

// ---- cross-block helpers ----
__device__ __forceinline__ float ldc_f(const float* p) {
  return __hip_atomic_load(p, __ATOMIC_RELAXED, __HIP_MEMORY_SCOPE_AGENT);
}
__device__ __forceinline__ void stc_f(float* p, float v) {
  __hip_atomic_store(p, v, __ATOMIC_RELAXED, __HIP_MEMORY_SCOPE_AGENT);
}
__device__ __forceinline__ void stc_u32(unsigned* p, unsigned v) {
  __hip_atomic_store(p, v, __ATOMIC_RELAXED, __HIP_MEMORY_SCOPE_AGENT);
}
__device__ __forceinline__ unsigned long long ldc_u64(const unsigned long long* p) {
  return __hip_atomic_load(p, __ATOMIC_RELAXED, __HIP_MEMORY_SCOPE_AGENT);
}
__device__ __forceinline__ void stc_u64(unsigned long long* p, unsigned long long v) {
  __hip_atomic_store(p, v, __ATOMIC_RELAXED, __HIP_MEMORY_SCOPE_AGENT);
}

// pack 8 consecutive fp32 -> bf16 fragment
__device__ __forceinline__ short8v packf(const float* p) {
  float4 e0 = *(const float4*)p, e1 = *(const float4*)(p + 4);
  short8v x;
  x[0] = (short)f2bf(e0.x); x[1] = (short)f2bf(e0.y);
  x[2] = (short)f2bf(e0.z); x[3] = (short)f2bf(e0.w);
  x[4] = (short)f2bf(e1.x); x[5] = (short)f2bf(e1.y);
  x[6] = (short)f2bf(e1.z); x[7] = (short)f2bf(e1.w);
  return x;
}

// ---------- generic fp32 -> bf16 cast ----------
__global__ __launch_bounds__(256) void cast_kernel(const float4* __restrict__ src,
                                                   uint2* __restrict__ dst, int n4) {
  for (int i = blockIdx.x * blockDim.x + threadIdx.x; i < n4; i += gridDim.x * blockDim.x) {
    float4 v = src[i];
    uint2 p;
    p.x = (unsigned)f2bf(v.x) | ((unsigned)f2bf(v.y) << 16);
    p.y = (unsigned)f2bf(v.z) | ((unsigned)f2bf(v.w) << 16);
    dst[i] = p;
  }
}

// ---------- fp32 -> fp8 e4m3 FTZ cast (4 elems -> 1 dword) ----------
__global__ __launch_bounds__(256) void cast8_kernel(const float4* __restrict__ src,
                                                    unsigned* __restrict__ dst, int n4) {
  for (int i = blockIdx.x * blockDim.x + threadIdx.x; i < n4; i += gridDim.x * blockDim.x) {
    float4 v = src[i];
    unsigned p = (unsigned)f2fp8z(v.x) | ((unsigned)f2fp8z(v.y) << 8) |
                 ((unsigned)f2fp8z(v.z) << 16) | ((unsigned)f2fp8z(v.w) << 24);
    dst[i] = p;
  }
}

// ---------- bridge: h0 = tanh(ef @ Wb^T + bb) ----------
__global__ __launch_bounds__(256) void bridge_kernel(const float* __restrict__ ef,
                                                     const float* __restrict__ Wb,
                                                     const float* __restrict__ bb,
                                                     float* __restrict__ h0out,
                                                     unsigned short* __restrict__ hb0) {
  __shared__ float efs[H2n];
  const int b = blockIdx.x >> 2, jq = blockIdx.x & 3;
  const int j = jq * 256 + threadIdx.x;
  for (int i = threadIdx.x; i < H2n; i += 256) efs[i] = ef[(size_t)b * H2n + i];
  __syncthreads();
  const float* wr = Wb + (size_t)j * H2n;
  float acc = bb[j];
  for (int k = 0; k < H2n; k += 4) {
    float4 wv = *(const float4*)&wr[k];
    acc += efs[k] * wv.x + efs[k + 1] * wv.y + efs[k + 2] * wv.z + efs[k + 3] * wv.w;
  }
  float th = tanhf(acc);
  h0out[(size_t)b * Hn + j] = th;
  hb0[(size_t)b * Hn + j] = f2bf(th);
}

// ---------- proj_key MFMA GEMM: f32 A packed on the fly, fp8 output ----------
__global__ __launch_bounds__(256) void pk_gemm(const float* __restrict__ A,
                                               const unsigned short* __restrict__ Bw,
                                               unsigned char* __restrict__ pk8) {
  const int bid = blockIdx.x;  // 4096 = 256 mt x 16 nt
  const int mt = bid >> 4, nt = bid & 15;
  const int w = threadIdx.x >> 6, lane = threadIdx.x & 63;
  const int lm = lane & 15, lk = lane >> 4, ko = lk * 8;
  const float* arow = A + (size_t)(mt * 64 + w * 16 + lm) * 2048 + ko;
  const unsigned short* b0 = Bw + (size_t)(nt * 64 + lm) * 2048 + ko;
  const unsigned short* b1 = Bw + (size_t)(nt * 64 + 16 + lm) * 2048 + ko;
  const unsigned short* b2 = Bw + (size_t)(nt * 64 + 32 + lm) * 2048 + ko;
  const unsigned short* b3 = Bw + (size_t)(nt * 64 + 48 + lm) * 2048 + ko;
  floatx4 c0 = {0,0,0,0}, c1 = {0,0,0,0}, c2 = {0,0,0,0}, c3 = {0,0,0,0};
  for (int k = 0; k < 2048; k += 32) {
    short8v a = packf(arow + k);
    c0 = MFMA(a, ldf(b0 + k), c0);
    c1 = MFMA(a, ldf(b1 + k), c1);
    c2 = MFMA(a, ldf(b2 + k), c2);
    c3 = MFMA(a, ldf(b3 + k), c3);
  }
  const int m = mt * 64 + w * 16 + lk * 4;
  const int j = nt * 64 + lm;
#pragma unroll
  for (int r = 0; r < 4; ++r) {
    unsigned char* row = pk8 + (size_t)(m + r) * 1024 + j;
    row[0]  = f2fp8z(c0[r]);
    row[16] = f2fp8z(c1[r]);
    row[32] = f2fp8z(c2[r]);
    row[48] = f2fp8z(c3[r]);
  }
}

// ---------- decoder persistent kernel ----------
struct DA {
  const float* emb; const float* v; const float* bih; const float* bhh;
  const unsigned char* pk8; const unsigned char* ehb8;
  const unsigned short* Wih; const unsigned short* Whh;
  const unsigned short* Wpre; const unsigned short* Wq;
  float* hbuf; unsigned short* hbR; float* qbuf; float* wbuf; float* psump;
  unsigned short* ctxR; unsigned* bar; float* out;
};

// counter+generation full-grid barrier (R0-verified). Used at A->C.
__device__ __forceinline__ void gbar(unsigned* bar, int tid, unsigned idx, int inv) {
  asm volatile("s_waitcnt vmcnt(0)" ::: "memory");
  __syncthreads();
  if (tid == 0) {
    unsigned old = __hip_atomic_fetch_add(bar, 1u, __ATOMIC_RELAXED, __HIP_MEMORY_SCOPE_AGENT);
    if (old + 1u == (unsigned)NBLK * idx) {
      __hip_atomic_store(bar + 32, idx, __ATOMIC_RELAXED, __HIP_MEMORY_SCOPE_AGENT);
    } else {
      unsigned g;
      do {
        __builtin_amdgcn_s_sleep(2);
        g = __hip_atomic_load(bar + 32, __ATOMIC_RELAXED, __HIP_MEMORY_SCOPE_AGENT);
      } while (g < idx);
    }
  }
  __syncthreads();
  if (inv) __builtin_amdgcn_fence(__ATOMIC_ACQUIRE, "agent");
}

// Full-grid barrier with pk8 prefetch during the poll (P0 only; all blocks).
__device__ __forceinline__ void gbar_pk(const DA& a, unsigned* bar, int tid, unsigned idx,
                                        int inv, int b, int sc4, int w,
                                        int lane, uint4* pkr8) {
  asm volatile("s_waitcnt vmcnt(0)" ::: "memory");
  __syncthreads();
  __builtin_amdgcn_sched_barrier(0);
#pragma unroll
  for (int i = 0; i < 4; ++i) {
    const unsigned char* prow =
        a.pk8 + ((size_t)b * Sn + sc4 * 64 + w * 4 + i) * 1024 + lane * 16;
    pkr8[i] = *(const uint4*)prow;
  }
  __builtin_amdgcn_sched_barrier(0);
  if (tid == 0) {
    unsigned old = __hip_atomic_fetch_add(bar, 1u, __ATOMIC_RELAXED, __HIP_MEMORY_SCOPE_AGENT);
    if (old + 1u == (unsigned)NBLK * idx) {
      __hip_atomic_store(bar + 32, idx, __ATOMIC_RELAXED, __HIP_MEMORY_SCOPE_AGENT);
    } else {
      unsigned g;
      do {
        __builtin_amdgcn_s_sleep(2);
        g = __hip_atomic_load(bar + 32, __ATOMIC_RELAXED, __HIP_MEMORY_SCOPE_AGENT);
      } while (g < idx);
    }
  }
  __syncthreads();
  if (inv) __builtin_amdgcn_fence(__ATOMIC_ACQUIRE, "agent");
}

// C->D one-way flag: gate blocks drain gate_c stores and bump bar[512];
// they do NOT wait. Pre blocks poll for 128 gate arrivals before pre_d.
__device__ __forceinline__ void gateC_signal(unsigned* bar, int tid) {
  asm volatile("s_waitcnt vmcnt(0)" ::: "memory");
  __syncthreads();
  if (tid == 0)
    __hip_atomic_fetch_add(bar + 512, 1u, __ATOMIC_RELAXED, __HIP_MEMORY_SCOPE_AGENT);
}
__device__ __forceinline__ void gateC_wait(unsigned* bar, int tid, unsigned tgt) {
  __syncthreads();
  if (tid == 0) {
    while (__hip_atomic_load(bar + 512, __ATOMIC_RELAXED, __HIP_MEMORY_SCOPE_AGENT) < tgt)
      __builtin_amdgcn_s_sleep(1);
  }
  __syncthreads();
}

// D->A producer flag: the 128 pre blocks drain + bump bar[544]; ALL blocks
// wait for 128*(t+1), issuing next-phA's pk8 prefetch during the poll.
__device__ __forceinline__ void preD_wait_pk(const DA& a, unsigned* bar, int tid,
                                             unsigned tgt, int inv, int isGate,
                                             int b, int sc4, int w, int lane,
                                             uint4* pkr8) {
  if (!isGate) {
    asm volatile("s_waitcnt vmcnt(0)" ::: "memory");
    __syncthreads();
    if (tid == 0)
      __hip_atomic_fetch_add(bar + 544, 1u, __ATOMIC_RELAXED, __HIP_MEMORY_SCOPE_AGENT);
  } else {
    __syncthreads();
  }
  __builtin_amdgcn_sched_barrier(0);
#pragma unroll
  for (int i = 0; i < 4; ++i) {
    const unsigned char* prow =
        a.pk8 + ((size_t)b * Sn + sc4 * 64 + w * 4 + i) * 1024 + lane * 16;
    pkr8[i] = *(const uint4*)prow;
  }
  __builtin_amdgcn_sched_barrier(0);
  if (tid == 0) {
    while (__hip_atomic_load(bar + 544, __ATOMIC_RELAXED, __HIP_MEMORY_SCOPE_AGENT) < tgt)
      __builtin_amdgcn_s_sleep(1);
  }
  __syncthreads();
  if (inv) __builtin_amdgcn_fence(__ATOMIC_ACQUIRE, "agent");
}

// Phase A: energies (fp8 pk from poll-window registers, HW decode) -> weights
// -> [4-way b-group flag sync] -> ctx quarter from the LDS-RESIDENT ehb8 slice
// ([k][tid*16] layout). Zero per-step global loads for ehb.
__device__ __forceinline__ void phA(const DA& a, char* dsm, int bid, int tid,
                                    int w, int lane, int t, uint4* pkr8) {
  const int b = bid >> 2, sc4 = bid & 3;
  float* w_s = (float*)(dsm + SCR);          // 64 floats
  float* q_s = (float*)(dsm + SCR + 1024);   // 1024 floats
  if (tid < 256) {
    const unsigned long long* qp = (const unsigned long long*)(a.qbuf + (size_t)b * Hn) + tid * 2;
    unsigned long long u0 = ldc_u64(qp), u1 = ldc_u64(qp + 1);
    union { unsigned long long u; float f[2]; } x0, x1; x0.u = u0; x1.u = u1;
    q_s[tid * 4] = x0.f[0]; q_s[tid * 4 + 1] = x0.f[1];
    q_s[tid * 4 + 2] = x1.f[0]; q_s[tid * 4 + 3] = x1.f[1];
  }
  __syncthreads();
  float qr[16], vr[16];
  const float* vp = a.v + lane * 16;
#pragma unroll
  for (int i = 0; i < 16; i += 4) {
    *(float4*)&qr[i] = *(const float4*)&q_s[lane * 16 + i];
    *(float4*)&vr[i] = *(const float4*)(vp + i);
  }
#pragma unroll
  for (int i = 0; i < 4; ++i) {
    float ep = 0.f;
    unsigned pw[4] = { pkr8[i].x, pkr8[i].y, pkr8[i].z, pkr8[i].w };
#pragma unroll
    for (int d = 0; d < 4; ++d) {
      floatx2 lo = dec2lo(pw[d]), hi = dec2hi(pw[d]);
      ep += vr[4 * d]     * tanh_f(qr[4 * d]     + lo[0]);
      ep += vr[4 * d + 1] * tanh_f(qr[4 * d + 1] + lo[1]);
      ep += vr[4 * d + 2] * tanh_f(qr[4 * d + 2] + hi[0]);
      ep += vr[4 * d + 3] * tanh_f(qr[4 * d + 3] + hi[1]);
    }
#pragma unroll
    for (int m = 1; m < 64; m <<= 1) ep += __shfl_xor(ep, m, 64);
    if (lane == 0) {
      float wv = __expf(ep - 20.f);  // |e| <= sum|v| ~ 16.5: fixed shift safe
      w_s[w * 4 + i] = wv;
      stc_f(a.wbuf + (size_t)b * Sn + sc4 * 64 + w * 4 + i, wv);
    }
  }
  __syncthreads();
  if (tid < 64) {
    float wv = w_s[tid];
#pragma unroll
    for (int m = 1; m < 64; m <<= 1) wv += __shfl_xor(wv, m, 64);
    if (tid == 0) stc_f(a.psump + sc4 * 64 + b, wv);
  }
  // ---- 4-way b-group flag sync ----
  asm volatile("s_waitcnt vmcnt(0)" ::: "memory");
  __syncthreads();
  if (tid == 0) stc_u32(&a.bar[64 + (b << 2) + sc4], (unsigned)(t + 1));
  if (tid < 4) {
    while (__hip_atomic_load(&a.bar[64 + (b << 2) + tid], __ATOMIC_RELAXED,
                             __HIP_MEMORY_SCOPE_AGENT) < (unsigned)(t + 1))
      __builtin_amdgcn_s_sleep(1);
  }
  __syncthreads();
  // ---- A2: normalized context -> ctxR slot t%WCTX (LDS ehb8 + HW decode) ----
  const int ls = lane >> 1, ldcx = lane & 1;
  const int dchunk = w * 2 + ldcx;  // 0..31 (16 fp8 each) within the sc4 quarter
  float* wn = (float*)(dsm + SCR);  // reuse: 256 normalized weights
  float psinv = 1.f / (ldc_f(a.psump + b) + ldc_f(a.psump + 64 + b) +
                       ldc_f(a.psump + 128 + b) + ldc_f(a.psump + 192 + b));
  if (tid < 256) wn[tid] = ldc_f(a.wbuf + (size_t)b * Sn + tid) * psinv;
  __syncthreads();
  float acc[16] = {};
#pragma unroll
  for (int k = 0; k < 8; ++k) {
    uint4 e = *(const uint4*)(dsm + EHL + (size_t)k * 16384 + (size_t)tid * 16);
    float wf = wn[ls + k * 32];
    dec4f(e.x, wf, acc);
    dec4f(e.y, wf, acc + 4);
    dec4f(e.z, wf, acc + 8);
    dec4f(e.w, wf, acc + 12);
  }
#pragma unroll
  for (int m = 2; m < 64; m <<= 1) {
#pragma unroll
    for (int e2 = 0; e2 < 16; ++e2) acc[e2] += __shfl_xor(acc[e2], m, 64);
  }
  if (ls == 0) {
    union { unsigned long long u[4]; unsigned short s[16]; } p;
#pragma unroll
    for (int e2 = 0; e2 < 16; ++e2) p.s[e2] = f2bf(acc[e2]);
    unsigned long long* dst = (unsigned long long*)(
        a.ctxR + (size_t)(t % WCTX) * Bn * H2n + (size_t)b * H2n + sc4 * 512 + dchunk * 16);
    stc_u64(dst, p.u[0]); stc_u64(dst + 1, p.u[1]);
    stc_u64(dst + 2, p.u[2]); stc_u64(dst + 3, p.u[3]);
  }
}

// Phase C, gate blocks: weights streamed from global/L2 (R5-verified neutral)
__device__ __forceinline__ void gate_c(const DA& a, char* dsm, int j0, int w,
                                       int lane, int tid, int t, int cur, int nxt) {
  float* scr = (float*)(dsm + SCR);  // [4 gate][64 b][8 j]
  for (int i = tid; i < 2048; i += NTHR) scr[i] = 0.f;
  __syncthreads();
  const int mt = w & 3, ks = w >> 2;
  const int lm = lane & 15, lk = lane >> 4;
  const int arow = mt * 16 + lm, jb = lm & 7;
  const unsigned short* ctxrow =
      a.ctxR + (size_t)(t % WCTX) * Bn * H2n + (size_t)arow * H2n + lk * 8;
  const unsigned short* hrow =
      a.hbR + (size_t)(t % WH) * Bn * Hn + (size_t)arow * Hn + lk * 8;
  const unsigned short* bi0 = a.Wih + (size_t)(0 * Hn + j0 + jb) * 2560 + 512 + lk * 8;
  const unsigned short* bi1 = a.Wih + (size_t)(1 * Hn + j0 + jb) * 2560 + 512 + lk * 8;
  const unsigned short* bi2 = a.Wih + (size_t)(2 * Hn + j0 + jb) * 2560 + 512 + lk * 8;
  const unsigned short* bh0 = a.Whh + (size_t)(0 * Hn + j0 + jb) * Hn + lk * 8;
  const unsigned short* bh1 = a.Whh + (size_t)(1 * Hn + j0 + jb) * Hn + lk * 8;
  const unsigned short* bh2 = a.Whh + (size_t)(2 * Hn + j0 + jb) * Hn + lk * 8;
  floatx4 ar = {0,0,0,0}, az = {0,0,0,0}, ain = {0,0,0,0}, ahn = {0,0,0,0};
#pragma unroll 4
  for (int kc = ks * 24; kc < ks * 24 + 24; ++kc) {
    if (kc < 64) {
      short8v x = ldf(ctxrow + kc * 32);
      ar  = MFMA(x, ldf(bi0 + kc * 32), ar);
      az  = MFMA(x, ldf(bi1 + kc * 32), az);
      ain = MFMA(x, ldf(bi2 + kc * 32), ain);
    } else {
      const int c = kc - 64;
      short8v x = ldf(hrow + c * 32);
      ar  = MFMA(x, ldf(bh0 + c * 32), ar);
      az  = MFMA(x, ldf(bh1 + c * 32), az);
      ahn = MFMA(x, ldf(bh2 + c * 32), ahn);
    }
  }
  if (lm < 8) {
#pragma unroll
    for (int r = 0; r < 4; ++r) {
      const int bb = mt * 16 + lk * 4 + r;
      atomicAdd(&scr[(0 * 64 + bb) * 8 + jb], ar[r]);
      atomicAdd(&scr[(1 * 64 + bb) * 8 + jb], az[r]);
      atomicAdd(&scr[(2 * 64 + bb) * 8 + jb], ain[r]);
      atomicAdd(&scr[(3 * 64 + bb) * 8 + jb], ahn[r]);
    }
  }
  __syncthreads();
  if (tid < 256) {
    const int bb = tid >> 2, jj = (tid & 3) * 2;
    float* gil = (float*)(dsm + GIL);
    float hn2[2];
#pragma unroll
    for (int u = 0; u < 2; ++u) {
      const int j = jj + u, jg = j0 + j;
      float grv = scr[(0 * 64 + bb) * 8 + j] + gil[(0 * 64 + bb) * 8 + j] + a.bhh[jg];
      float gzv = scr[(1 * 64 + bb) * 8 + j] + gil[(1 * 64 + bb) * 8 + j] + a.bhh[Hn + jg];
      float ginv = scr[(2 * 64 + bb) * 8 + j] + gil[(2 * 64 + bb) * 8 + j];
      float ghnv = scr[(3 * 64 + bb) * 8 + j] + a.bhh[2 * Hn + jg];
      float rr = sigm(grv), zz = sigm(gzv);
      float nn = tanh_f(ginv + rr * ghnv);
      float hold = a.hbuf[(size_t)cur * Bn * Hn + (size_t)bb * Hn + jg];
      float hnew = (1.f - zz) * nn + zz * hold;
      hn2[u] = hnew;
      a.hbuf[(size_t)nxt * Bn * Hn + (size_t)bb * Hn + jg] = hnew;
      a.out[((size_t)bb * Tn + t) * Hn + jg] = hnew;
      if (t == Tn - 1) a.out[(size_t)Bn * Tn * Hn + (size_t)bb * Hn + jg] = hnew;
    }
    unsigned hpack = (unsigned)f2bf(hn2[0]) | ((unsigned)f2bf(hn2[1]) << 16);
    stc_u32((unsigned*)(a.hbR + (size_t)((t + 1) % WH) * Bn * Hn +
                        (size_t)bb * Hn + j0 + jj), hpack);
  }
}

// Phase C, pre blocks: weights streamed from global/L2
__device__ __forceinline__ void pre_c(const DA& a, char* dsm, int j0, int w,
                                      int lane, int tid, int t) {
  float* prep = (float*)(dsm + PREP);  // [64][8]
  for (int i = tid; i < 512; i += NTHR) prep[i] = 0.f;
  __syncthreads();
  const int mt = w & 3, ks = w >> 2;
  const int lm = lane & 15, lk = lane >> 4;
  const int arow = mt * 16 + lm, jb = lm & 7;
  const unsigned short* ctxrow =
      a.ctxR + (size_t)(t % WCTX) * Bn * H2n + (size_t)arow * H2n + lk * 8;
  const float* ep = a.emb + ((size_t)arow * Tn + t) * En + lk * 8;
  const unsigned short* we = a.Wpre + (size_t)(j0 + jb) * 3584 + lk * 8;
  const unsigned short* wc = a.Wpre + (size_t)(j0 + jb) * 3584 + 1536 + lk * 8;
  floatx4 acc = {0,0,0,0};
#pragma unroll 4
  for (int kc = ks * 20; kc < ks * 20 + 20; ++kc) {
    if (kc < 16) {
      acc = MFMA(packf(ep + kc * 32), ldf(we + kc * 32), acc);
    } else {
      const int c = kc - 16;
      acc = MFMA(ldf(ctxrow + c * 32), ldf(wc + c * 32), acc);
    }
  }
  if (lm < 8) {
#pragma unroll
    for (int r = 0; r < 4; ++r)
      atomicAdd(&prep[(mt * 16 + lk * 4 + r) * 8 + jb], acc[r]);
  }
  __syncthreads();
}

// Phase D, pre blocks: weights streamed from global/L2
__device__ __forceinline__ void pre_d(const DA& a, char* dsm, int j0, int w,
                                      int lane, int tid, int t, int hslot, int doPre) {
  float* scr = (float*)(dsm + SCR2);  // [2][64][8] : P then Q
  for (int i = tid; i < 1024; i += NTHR) scr[i] = 0.f;
  __syncthreads();
  const int mt = w & 3, part = w >> 2;
  const int lm = lane & 15, lk = lane >> 4;
  const int arow = mt * 16 + lm, jb = lm & 7;
  const unsigned short* hrow =
      a.hbR + (size_t)hslot * Bn * Hn + (size_t)arow * Hn + lk * 8;
  const int isQ = part >> 1;
  const unsigned short* wbase = isQ
      ? a.Wq + (size_t)(j0 + jb) * Hn + lk * 8
      : a.Wpre + (size_t)(j0 + jb) * 3584 + 512 + lk * 8;
  if (doPre || isQ) {
    floatx4 acc = {0,0,0,0};
    const int k0 = (part & 1) * 16;
#pragma unroll 4
    for (int kh = k0; kh < k0 + 16; ++kh)
      acc = MFMA(ldf(hrow + kh * 32), ldf(wbase + kh * 32), acc);
    if (lm < 8) {
#pragma unroll
      for (int r = 0; r < 4; ++r)
        atomicAdd(&scr[(isQ * 64 + mt * 16 + lk * 4 + r) * 8 + jb], acc[r]);
    }
  }
  __syncthreads();
  if (tid < 256) {
    const int bb = tid >> 2, jj = (tid & 3) * 2;
    float* prep = (float*)(dsm + PREP);
#pragma unroll
    for (int u = 0; u < 2; ++u) {
      const int j = jj + u, jg = j0 + j;
      if (doPre) {
        float pv = scr[(0 * 64 + bb) * 8 + j] + prep[bb * 8 + j];
        a.out[(size_t)Bn * Tn * Hn + (size_t)Bn * Hn + ((size_t)bb * Tn + t) * Hn + jg] = pv;
      }
      stc_f(a.qbuf + (size_t)bb * Hn + jg, scr[(1 * 64 + bb) * 8 + j]);
    }
  }
}

// Phase D, gate blocks (always streamed Wih from global)
__device__ __forceinline__ void gi_compute(const DA& a, char* dsm, int j0, int w,
                                           int lane, int t1) {
  const int mt = w & 3, g = w >> 2;
  if (g >= 3) return;
  const int lm = lane & 15, lk = lane >> 4;
  const int arow = mt * 16 + lm;
  const unsigned short* wrow = a.Wih + (size_t)(g * Hn + j0 + (lm & 7)) * 2560 + lk * 8;
  const float* ep = a.emb + ((size_t)arow * Tn + t1) * En + lk * 8;
  floatx4 acc = {0,0,0,0};
#pragma unroll 4
  for (int kk = 0; kk < 16; ++kk)
    acc = MFMA(packf(ep + kk * 32), ldf(wrow + kk * 32), acc);
  if (lm < 8) {
    float* gil = (float*)(dsm + GIL);
    float bv = a.bih[g * Hn + j0 + lm];
#pragma unroll
    for (int r = 0; r < 4; ++r)
      gil[(g * 64 + mt * 16 + lk * 4 + r) * 8 + lm] = acc[r] + bv;
  }
}

// waves_per_eu(4,4): exactly 4 waves/EU. ehb8 slice (128 KB) is LDS-resident;
// weights stream from L2 (R5-verified wall-neutral).
__global__ void __attribute__((amdgpu_flat_work_group_size(1024, 1024),
                               amdgpu_waves_per_eu(4, 4)))
dec_kernel(DA a) {
  extern __shared__ char dsm[];
  const int tid = threadIdx.x, bid = blockIdx.x;
  const int w = tid >> 6, lane = tid & 63;
  const bool isGate = bid < 128;
  const int j0 = (isGate ? bid : bid - 128) * 8;
  const int pb = bid >> 2, psc4 = bid & 3;  // phA partition (all blocks)

  // ---- stage this block's 128 KB ehb8 slice into LDS, [k][tid*16] layout ----
  {
    const int ls = lane >> 1, ldcx = lane & 1;
    const int dchunk = w * 2 + ldcx;
    const unsigned char* ebase =
        a.ehb8 + (size_t)pb * Sn * H2n + psc4 * 512 + dchunk * 16;
#pragma unroll
    for (int k = 0; k < 8; ++k) {
      uint4 t4 = *(const uint4*)(ebase + (size_t)(ls + k * 32) * H2n);
      *(uint4*)(dsm + EHL + (size_t)k * 16384 + (size_t)tid * 16) = t4;
    }
  }
  __syncthreads();

  uint4 pkr8[4];
  unsigned bi = 1;
  // P0: gate blocks -> gi(0); pre blocks -> q(0) from h0 (hbR slot 0)
  if (isGate) gi_compute(a, dsm, j0, w, lane, 0);
  else pre_d(a, dsm, j0, w, lane, tid, 0, 0, 0);
  gbar_pk(a, a.bar, tid, bi++, 0, pb, psc4, w, lane, pkr8);

  for (int t = 0; t < Tn; ++t) {
    const int cur = t & 1, nxt = cur ^ 1;
    phA(a, dsm, bid, tid, w, lane, t, pkr8);  // internal 4-way sync
    gbar(a.bar, tid, bi++, 0);                // A->C: full grid (ctx for all b)
    if (isGate) {
      gate_c(a, dsm, j0, w, lane, tid, t, cur, nxt);
      gateC_signal(a.bar, tid);               // h(t+1) published; no wait
      if (t + 1 < Tn) gi_compute(a, dsm, j0, w, lane, t + 1);
    } else {
      pre_c(a, dsm, j0, w, lane, tid, t);
      gateC_wait(a.bar, tid, 128u * (unsigned)(t + 1));  // need h(t+1)
      pre_d(a, dsm, j0, w, lane, tid, t, (t + 1) % WH, 1);
    }
    // D->A: wait on the 128 pre producers (qbuf); all blocks prefetch pk8
    preD_wait_pk(a, a.bar, tid, 128u * (unsigned)(t + 1), (t & 7) == 7,
                 isGate, pb, psc4, w, lane, pkr8);
  }
}

// ---------- host launcher ----------
extern "C" void kernel_launch(void* const* d_in, const int* in_sizes, int n_in,
                              void* d_out, int out_size, void* d_ws, size_t ws_size,
                              hipStream_t stream) {
  (void)in_sizes; (void)n_in; (void)out_size; (void)ws_size;
  const float* emb = (const float*)d_in[0];
  const float* eh  = (const float*)d_in[1];
  const float* ef  = (const float*)d_in[2];
  const float* Wb  = (const float*)d_in[5];
  const float* bb  = (const float*)d_in[6];
  const float* Wk  = (const float*)d_in[7];
  const float* Wq  = (const float*)d_in[8];
  const float* v   = (const float*)d_in[9];
  const float* Wih = (const float*)d_in[10];
  const float* Whh = (const float*)d_in[11];
  const float* bih = (const float*)d_in[12];
  const float* bhh = (const float*)d_in[13];
  const float* Wpre= (const float*)d_in[14];
  float* out = (float*)d_out;

  // Compact layout: both steady-state streams (ehb, pk) are fp8.
  char* wsb = (char*)d_ws;
  unsigned char*  ehb8 = (unsigned char*)(wsb + 0);             // 33,554,432 (fp8)
  unsigned char*  pk8  = (unsigned char*)(wsb + 33554432);      // 16,777,216 (fp8)
  unsigned short* Wihb = (unsigned short*)(wsb + 50331648);     // 15,728,640
  unsigned short* Whhb = (unsigned short*)(wsb + 66060288);     //  6,291,456
  unsigned short* Wpreb= (unsigned short*)(wsb + 72351744);     //  7,340,032
  unsigned short* Wqb  = (unsigned short*)(wsb + 79691776);     //  2,097,152
  unsigned short* Wkb  = (unsigned short*)(wsb + 81788928);     //  4,194,304 (dead after pk_gemm)
  // rotated buffers overlay the Wkb region (written only after pk_gemm consumed it)
  unsigned short* ctxR = (unsigned short*)(wsb + 81788928);     // 10 x 262,144 = 2,621,440
  unsigned short* hbR  = (unsigned short*)(wsb + 84410368);     // 12 x 131,072 = 1,572,864 (ends 85,983,232)
  float* hbuf = (float*)(wsb + 85983232);                       //    524,288
  float* qbuf = (float*)(wsb + 86507520);                       //    262,144
  float* wbuf = (float*)(wsb + 86769664);                       //     65,536
  float* psump= (float*)(wsb + 86835200);                       //      4,096
  unsigned* bar = (unsigned*)(wsb + 86839296);                  //      4,096

  hipMemsetAsync(bar, 0, 4096, stream);
  cast8_kernel<<<2048, 256, 0, stream>>>((const float4*)eh, (unsigned*)ehb8,
                                         Bn * Sn * H2n / 4);
  cast_kernel<<<2048, 256, 0, stream>>>((const float4*)Wih, (uint2*)Wihb, 3 * Hn * 2560 / 4);
  cast_kernel<<<1024, 256, 0, stream>>>((const float4*)Whh, (uint2*)Whhb, 3 * Hn * Hn / 4);
  cast_kernel<<<1024, 256, 0, stream>>>((const float4*)Wpre, (uint2*)Wpreb, Hn * 3584 / 4);
  cast_kernel<<<512, 256, 0, stream>>>((const float4*)Wq, (uint2*)Wqb, Hn * Hn / 4);
  cast_kernel<<<512, 256, 0, stream>>>((const float4*)Wk, (uint2*)Wkb, Hn * H2n / 4);
  pk_gemm<<<4096, 256, 0, stream>>>(eh, Wkb, pk8);
  // bridge writes hbR slot 0 (inside the ex-Wkb region) -> must run AFTER pk_gemm
  bridge_kernel<<<256, 256, 0, stream>>>(ef, Wb, bb, hbuf, hbR);

  DA da;
  da.emb = emb; da.v = v; da.bih = bih; da.bhh = bhh;
  da.pk8 = pk8; da.ehb8 = ehb8;
  da.Wih = Wihb; da.Whh = Whhb; da.Wpre = Wpreb; da.Wq = Wqb;
  da.hbuf = hbuf; da.hbR = hbR; da.qbuf = qbuf; da.wbuf = wbuf; da.psump = psump;
  da.ctxR = ctxR; da.bar = bar; da.out = out;

  hipFuncSetAttribute(reinterpret_cast<const void*>(&dec_kernel),
                      hipFuncAttributeMaxDynamicSharedMemorySize, LDS_BYTES);
  void* kp[] = { (void*)&da };
  hipLaunchCooperativeKernel(reinterpret_cast<const void*>(&dec_kernel),
                             dim3(NBLK), dim3(NTHR), kp, LDS_BYTES, stream);
}

// Round 18
// 11150.318 us; speedup vs baseline: 1.3856x; 1.3856x over previous
//
#include <hip/hip_runtime.h>

#define Bn 64
#define Sn 256
#define Tn 128
#define Hn 1024
#define En 512
#define H2n 2048
#define NBLK 256
#define NTHR 1024

// rotation depths (reuse distance > fence period 8 + read window)
#define WCTX 10
#define WH 12

// LDS byte offsets (dynamic shared) -- R15 map: weights LDS-resident
#define GW 0
#define PWc 0
#define PWh 32768
#define PWq 49152
#define PWe 65536
#define PREP 73728
#define SCR2 75776
#define PKL 81920          // pre blocks only: 64 KB fp8 pk slice
#define SCR 147456
#define GIL 155648
#define LDS_BYTES 161792

typedef __attribute__((ext_vector_type(8))) short short8v;
typedef __attribute__((ext_vector_type(4))) float floatx4;
typedef __attribute__((ext_vector_type(2))) float floatx2;

// HW OCP-fp8 decode if available (gfx940+/gfx950); else verified software path.
#if defined(__has_builtin)
#if __has_builtin(__builtin_amdgcn_cvt_pk_f32_fp8)
#define HW_FP8 1
#endif
#endif

__device__ __forceinline__ unsigned short f2bf(float f) {
  union { float f; unsigned u; } x; x.f = f;
  unsigned r = x.u + 0x7fffu + ((x.u >> 16) & 1u);
  return (unsigned short)(r >> 16);
}
__device__ __forceinline__ float bf2f(unsigned short u) {
  union { unsigned u; float f; } x; x.u = ((unsigned)u) << 16; return x.f;
}
__device__ __forceinline__ float sigm(float x) { return 1.f / (1.f + __expf(-x)); }
__device__ __forceinline__ float tanh_f(float x) {
  float e = __expf(2.f * x);
  return 1.f - 2.f / (e + 1.f);
}
__device__ __forceinline__ short8v ldf(const unsigned short* p) { return *(const short8v*)p; }
#define MFMA(a, b, c) __builtin_amdgcn_mfma_f32_16x16x32_bf16(a, b, c, 0, 0, 0)

// ---- fp8 e4m3fn FTZ codec (R11/R12/R15-verified in production) ----
__device__ __forceinline__ unsigned char f2fp8z(float f) {
  union { float f; unsigned u; } x; x.f = f;
  unsigned s = (x.u >> 24) & 0x80u;
  unsigned au = x.u & 0x7fffffffu;
  if (au >= 0x43e00000u) return (unsigned char)(s | 0x7Eu);   // clamp to 448
  if (au < 0x3c000000u) return (unsigned char)s;              // FTZ below 2^-7
  if (au < 0x3c800000u) return (unsigned char)(s | 0x08u);    // round to min normal
  unsigned r = au + 0x7ffffu + ((au >> 20) & 1u);             // RNE at bit 20
  unsigned e8 = ((r >> 23) & 0xffu) - 120u;
  unsigned m8 = (r >> 20) & 7u;
  return (unsigned char)(s | (e8 << 3) | m8);
}
__device__ __forceinline__ float dec1(unsigned b) {
  union { unsigned u; float f; } x;
  x.u = ((b & 0x80u) << 24) | ((b & 0x7fu) << 20);
  return x.f * 0x1p120f;
}
__device__ __forceinline__ floatx2 dec2lo(unsigned w) {
#ifdef HW_FP8
  return __builtin_amdgcn_cvt_pk_f32_fp8(w, false);
#else
  floatx2 r; r[0] = dec1(w & 0xffu); r[1] = dec1((w >> 8) & 0xffu); return r;
#endif
}
__device__ __forceinline__ floatx2 dec2hi(unsigned w) {
#ifdef HW_FP8
  return __builtin_amdgcn_cvt_pk_f32_fp8(w, true);
#else
  floatx2 r; r[0] = dec1((w >> 16) & 0xffu); r[1] = dec1(w >> 24); return r;
#endif
}

// ---- cross-block helpers ----
__device__ __forceinline__ float ldc_f(const float* p) {
  return __hip_atomic_load(p, __ATOMIC_RELAXED, __HIP_MEMORY_SCOPE_AGENT);
}
__device__ __forceinline__ void stc_f(float* p, float v) {
  __hip_atomic_store(p, v, __ATOMIC_RELAXED, __HIP_MEMORY_SCOPE_AGENT);
}
__device__ __forceinline__ void stc_u32(unsigned* p, unsigned v) {
  __hip_atomic_store(p, v, __ATOMIC_RELAXED, __HIP_MEMORY_SCOPE_AGENT);
}
__device__ __forceinline__ unsigned long long ldc_u64(const unsigned long long* p) {
  return __hip_atomic_load(p, __ATOMIC_RELAXED, __HIP_MEMORY_SCOPE_AGENT);
}
__device__ __forceinline__ void stc_u64(unsigned long long* p, unsigned long long v) {
  __hip_atomic_store(p, v, __ATOMIC_RELAXED, __HIP_MEMORY_SCOPE_AGENT);
}

// LDS-only barrier: drains lgkmcnt, NOT vmcnt. sched_barrier fences per the
// hoisting-hazard rule.
__device__ __forceinline__ void bar_lds() {
  __builtin_amdgcn_sched_barrier(0);
  asm volatile("s_waitcnt lgkmcnt(0)" ::: "memory");
  __builtin_amdgcn_s_barrier();
  __builtin_amdgcn_sched_barrier(0);
}

// pack 8 consecutive fp32 -> bf16 fragment
__device__ __forceinline__ short8v packf(const float* p) {
  float4 e0 = *(const float4*)p, e1 = *(const float4*)(p + 4);
  short8v x;
  x[0] = (short)f2bf(e0.x); x[1] = (short)f2bf(e0.y);
  x[2] = (short)f2bf(e0.z); x[3] = (short)f2bf(e0.w);
  x[4] = (short)f2bf(e1.x); x[5] = (short)f2bf(e1.y);
  x[6] = (short)f2bf(e1.z); x[7] = (short)f2bf(e1.w);
  return x;
}

// ---------- generic fp32 -> bf16 cast ----------
__global__ __launch_bounds__(256) void cast_kernel(const float4* __restrict__ src,
                                                   uint2* __restrict__ dst, int n4) {
  for (int i = blockIdx.x * blockDim.x + threadIdx.x; i < n4; i += gridDim.x * blockDim.x) {
    float4 v = src[i];
    uint2 p;
    p.x = (unsigned)f2bf(v.x) | ((unsigned)f2bf(v.y) << 16);
    p.y = (unsigned)f2bf(v.z) | ((unsigned)f2bf(v.w) << 16);
    dst[i] = p;
  }
}

// ---------- eh[b][s][d] f32 -> ehb8T[b][d][s] fp8 (LDS-tiled transpose) ----
// grid: 64 b x 4 s-tiles x 32 d-tiles = 8192 blocks, 256 thr; tile 64s x 64d.
__global__ __launch_bounds__(256) void cast8t_kernel(const float* __restrict__ src,
                                                     unsigned char* __restrict__ dst) {
  __shared__ unsigned char tile[64][68];
  const int bidx = blockIdx.x;
  const int b = bidx >> 7;
  const int st = (bidx >> 5) & 3;
  const int dt = bidx & 31;
  const int t = threadIdx.x;
  {
    const int sr = t >> 2, dc4 = (t & 3) * 16;
    const float* sp = src + ((size_t)b * Sn + st * 64 + sr) * H2n + dt * 64 + dc4;
#pragma unroll
    for (int j = 0; j < 16; j += 4) {
      float4 v = *(const float4*)(sp + j);
      tile[sr][dc4 + j]     = f2fp8z(v.x);
      tile[sr][dc4 + j + 1] = f2fp8z(v.y);
      tile[sr][dc4 + j + 2] = f2fp8z(v.z);
      tile[sr][dc4 + j + 3] = f2fp8z(v.w);
    }
  }
  __syncthreads();
  {
    const int dr = t >> 2, sc16 = (t & 3) * 16;
    union { unsigned char c[16]; uint4 v; } tmp;
#pragma unroll
    for (int j = 0; j < 16; ++j) tmp.c[j] = tile[sc16 + j][dr];
    unsigned char* dp = dst + (size_t)b * ((size_t)H2n * Sn)
                        + (size_t)(dt * 64 + dr) * Sn + st * 64 + sc16;
    *(uint4*)dp = tmp.v;
  }
}

// ---------- bridge: h0 = tanh(ef @ Wb^T + bb) ----------
__global__ __launch_bounds__(256) void bridge_kernel(const float* __restrict__ ef,
                                                     const float* __restrict__ Wb,
                                                     const float* __restrict__ bb,
                                                     float* __restrict__ h0out,
                                                     unsigned short* __restrict__ hb0) {
  __shared__ float efs[H2n];
  const int b = blockIdx.x >> 2, jq = blockIdx.x & 3;
  const int j = jq * 256 + threadIdx.x;
  for (int i = threadIdx.x; i < H2n; i += 256) efs[i] = ef[(size_t)b * H2n + i];
  __syncthreads();
  const float* wr = Wb + (size_t)j * H2n;
  float acc = bb[j];
  for (int k = 0; k < H2n; k += 4) {
    float4 wv = *(const float4*)&wr[k];
    acc += efs[k] * wv.x + efs[k + 1] * wv.y + efs[k + 2] * wv.z + efs[k + 3] * wv.w;
  }
  float th = tanhf(acc);
  h0out[(size_t)b * Hn + j] = th;
  hb0[(size_t)b * Hn + j] = f2bf(th);
}

// ---------- proj_key MFMA GEMM: f32 A packed on the fly, fp8 output ----------
__global__ __launch_bounds__(256) void pk_gemm(const float* __restrict__ A,
                                               const unsigned short* __restrict__ Bw,
                                               unsigned char* __restrict__ pk8) {
  const int bid = blockIdx.x;  // 4096 = 256 mt x 16 nt
  const int mt = bid >> 4, nt = bid & 15;
  const int w = threadIdx.x >> 6, lane = threadIdx.x & 63;
  const int lm = lane & 15, lk = lane >> 4, ko = lk * 8;
  const float* arow = A + (size_t)(mt * 64 + w * 16 + lm) * 2048 + ko;
  const unsigned short* b0 = Bw + (size_t)(nt * 64 + lm) * 2048 + ko;
  const unsigned short* b1 = Bw + (size_t)(nt * 64 + 16 + lm) * 2048 + ko;
  const unsigned short* b2 = Bw + (size_t)(nt * 64 + 32 + lm) * 2048 + ko;
  const unsigned short* b3 = Bw + (size_t)(nt * 64 + 48 + lm) * 2048 + ko;
  floatx4 c0 = {0,0,0,0}, c1 = {0,0,0,0}, c2 = {0,0,0,0}, c3 = {0,0,0,0};
  for (int k = 0; k < 2048; k += 32) {
    short8v a = packf(arow + k);
    c0 = MFMA(a, ldf(b0 + k), c0);
    c1 = MFMA(a, ldf(b1 + k), c1);
    c2 = MFMA(a, ldf(b2 + k), c2);
    c3 = MFMA(a, ldf(b3 + k), c3);
  }
  const int m = mt * 64 + w * 16 + lk * 4;
  const int j = nt * 64 + lm;
#pragma unroll
  for (int r = 0; r < 4; ++r) {
    unsigned char* row = pk8 + (size_t)(m + r) * 1024 + j;
    row[0]  = f2fp8z(c0[r]);
    row[16] = f2fp8z(c1[r]);
    row[32] = f2fp8z(c2[r]);
    row[48] = f2fp8z(c3[r]);
  }
}

// ---------- decoder persistent kernel ----------
struct DA {
  const float* emb; const float* v; const float* bih; const float* bhh;
  const unsigned char* pk8; const unsigned char* ehb8;  // ehb8 = TRANSPOSED [b][d][s]
  const unsigned short* Wih; const unsigned short* Whh;
  const unsigned short* Wpre; const unsigned short* Wq;
  float* hbuf; unsigned short* hbR; float* qbuf; float* wbuf; float* psump;
  unsigned short* ctxR; unsigned* bar; float* out;
};

// counter+generation full-grid barrier (R0-verified). Used at A->C.
__device__ __forceinline__ void gbar(unsigned* bar, int tid, unsigned idx, int inv) {
  asm volatile("s_waitcnt vmcnt(0)" ::: "memory");
  __syncthreads();
  if (tid == 0) {
    unsigned old = __hip_atomic_fetch_add(bar, 1u, __ATOMIC_RELAXED, __HIP_MEMORY_SCOPE_AGENT);
    if (old + 1u == (unsigned)NBLK * idx) {
      __hip_atomic_store(bar + 32, idx, __ATOMIC_RELAXED, __HIP_MEMORY_SCOPE_AGENT);
    } else {
      unsigned g;
      do {
        __builtin_amdgcn_s_sleep(2);
        g = __hip_atomic_load(bar + 32, __ATOMIC_RELAXED, __HIP_MEMORY_SCOPE_AGENT);
      } while (g < idx);
    }
  }
  __syncthreads();
  if (inv) __builtin_amdgcn_fence(__ATOMIC_ACQUIRE, "agent");
}

// Full-grid barrier with pk8 prefetch during the poll (P0 only; gates only).
__device__ __forceinline__ void gbar_pk(const DA& a, unsigned* bar, int tid, unsigned idx,
                                        int inv, int isGate, int b, int sc4, int w,
                                        int lane, uint4* pkr8) {
  asm volatile("s_waitcnt vmcnt(0)" ::: "memory");
  __syncthreads();
  __builtin_amdgcn_sched_barrier(0);
  if (isGate) {
#pragma unroll
    for (int i = 0; i < 4; ++i) {
      const unsigned char* prow =
          a.pk8 + ((size_t)b * Sn + sc4 * 64 + w * 4 + i) * 1024 + lane * 16;
      pkr8[i] = *(const uint4*)prow;
    }
  }
  __builtin_amdgcn_sched_barrier(0);
  if (tid == 0) {
    unsigned old = __hip_atomic_fetch_add(bar, 1u, __ATOMIC_RELAXED, __HIP_MEMORY_SCOPE_AGENT);
    if (old + 1u == (unsigned)NBLK * idx) {
      __hip_atomic_store(bar + 32, idx, __ATOMIC_RELAXED, __HIP_MEMORY_SCOPE_AGENT);
    } else {
      unsigned g;
      do {
        __builtin_amdgcn_s_sleep(2);
        g = __hip_atomic_load(bar + 32, __ATOMIC_RELAXED, __HIP_MEMORY_SCOPE_AGENT);
      } while (g < idx);
    }
  }
  __syncthreads();
  if (inv) __builtin_amdgcn_fence(__ATOMIC_ACQUIRE, "agent");
}

// C->D one-way flag: gate blocks drain gate_c stores and bump bar[512];
// they do NOT wait. Pre blocks poll for 128 gate arrivals before pre_d.
__device__ __forceinline__ void gateC_signal(unsigned* bar, int tid) {
  asm volatile("s_waitcnt vmcnt(0)" ::: "memory");
  __syncthreads();
  if (tid == 0)
    __hip_atomic_fetch_add(bar + 512, 1u, __ATOMIC_RELAXED, __HIP_MEMORY_SCOPE_AGENT);
}
__device__ __forceinline__ void gateC_wait(unsigned* bar, int tid, unsigned tgt) {
  __syncthreads();
  if (tid == 0) {
    while (__hip_atomic_load(bar + 512, __ATOMIC_RELAXED, __HIP_MEMORY_SCOPE_AGENT) < tgt)
      __builtin_amdgcn_s_sleep(1);
  }
  __syncthreads();
}

// D->A producer flag: the 128 pre blocks drain + bump bar[544]; ALL blocks
// wait for 128*(t+1); gate blocks issue next-phA's pk8 prefetch during the poll.
__device__ __forceinline__ void preD_wait_pk(const DA& a, unsigned* bar, int tid,
                                             unsigned tgt, int inv, int isGate,
                                             int b, int sc4, int w, int lane,
                                             uint4* pkr8) {
  if (!isGate) {
    asm volatile("s_waitcnt vmcnt(0)" ::: "memory");
    __syncthreads();
    if (tid == 0)
      __hip_atomic_fetch_add(bar + 544, 1u, __ATOMIC_RELAXED, __HIP_MEMORY_SCOPE_AGENT);
  } else {
    __syncthreads();
  }
  __builtin_amdgcn_sched_barrier(0);
  if (isGate) {
#pragma unroll
    for (int i = 0; i < 4; ++i) {
      const unsigned char* prow =
          a.pk8 + ((size_t)b * Sn + sc4 * 64 + w * 4 + i) * 1024 + lane * 16;
      pkr8[i] = *(const uint4*)prow;
    }
  }
  __builtin_amdgcn_sched_barrier(0);
  if (tid == 0) {
    while (__hip_atomic_load(bar + 544, __ATOMIC_RELAXED, __HIP_MEMORY_SCOPE_AGENT) < tgt)
      __builtin_amdgcn_s_sleep(1);
  }
  __syncthreads();
  if (inv) __builtin_amdgcn_fence(__ATOMIC_ACQUIRE, "agent");
}

// Phase A: energies (fp8 pk, HW decode) -> weights -> [4-way b-group flag
// sync] -> ctx quarter from TRANSPOSED ehb8T. Per wave-load the 16-lane group
// reads a 256-B contiguous segment (one d-row's 16 s) -- coalesced, ~8x fewer
// transactions than the old 32-B scattered pattern. Loads issued after
// energies (R15 schedule), completing at the flag-sync's vmcnt(0).
__device__ __forceinline__ void phA(const DA& a, char* dsm, int bid, int tid,
                                    int w, int lane, int t, uint4* pkr8, int isGate) {
  const int b = bid >> 2, sc4 = bid & 3;
  float* w_s = (float*)(dsm + SCR);          // 64 floats
  float* q_s = (float*)(dsm + SCR + 1024);   // 1024 floats
  if (tid < 256) {
    const unsigned long long* qp = (const unsigned long long*)(a.qbuf + (size_t)b * Hn) + tid * 2;
    unsigned long long u0 = ldc_u64(qp), u1 = ldc_u64(qp + 1);
    union { unsigned long long u; float f[2]; } x0, x1; x0.u = u0; x1.u = u1;
    q_s[tid * 4] = x0.f[0]; q_s[tid * 4 + 1] = x0.f[1];
    q_s[tid * 4 + 2] = x1.f[0]; q_s[tid * 4 + 3] = x1.f[1];
  }
  __syncthreads();
  if (!isGate) {
    // pk slice is LDS-resident (staged once at startup)
#pragma unroll
    for (int i = 0; i < 4; ++i)
      pkr8[i] = *(const uint4*)(dsm + PKL + (size_t)(w * 4 + i) * 1024 + lane * 16);
  }
  float qr[16], vr[16];
  const float* vp = a.v + lane * 16;
#pragma unroll
  for (int i = 0; i < 16; i += 4) {
    *(float4*)&qr[i] = *(const float4*)&q_s[lane * 16 + i];
    *(float4*)&vr[i] = *(const float4*)(vp + i);
  }
#pragma unroll
  for (int i = 0; i < 4; ++i) {
    float ep = 0.f;
    unsigned pw[4] = { pkr8[i].x, pkr8[i].y, pkr8[i].z, pkr8[i].w };
#pragma unroll
    for (int d = 0; d < 4; ++d) {
      floatx2 lo = dec2lo(pw[d]), hi = dec2hi(pw[d]);
      ep += vr[4 * d]     * tanh_f(qr[4 * d]     + lo[0]);
      ep += vr[4 * d + 1] * tanh_f(qr[4 * d + 1] + lo[1]);
      ep += vr[4 * d + 2] * tanh_f(qr[4 * d + 2] + hi[0]);
      ep += vr[4 * d + 3] * tanh_f(qr[4 * d + 3] + hi[1]);
    }
#pragma unroll
    for (int m = 1; m < 64; m <<= 1) ep += __shfl_xor(ep, m, 64);
    if (lane == 0) {
      float wv = __expf(ep - 20.f);  // |e| <= sum|v| ~ 16.5: fixed shift safe
      w_s[w * 4 + i] = wv;
      stc_f(a.wbuf + (size_t)b * Sn + sc4 * 64 + w * 4 + i, wv);
    }
  }
  // ---- A2 ehb8T prefetch: 8 uint4, 256-B contiguous segments (d-major) ----
  const int lg = lane >> 4, s0 = (lane & 15) * 16;
  const unsigned char* ebase = a.ehb8 + (size_t)b * 524288 + (size_t)sc4 * 131072
                               + (size_t)(w * 32 + lg * 8) * 256 + s0;
  uint4 er[8];
#pragma unroll
  for (int k = 0; k < 8; ++k) er[k] = *(const uint4*)(ebase + k * 256);
  bar_lds();  // w_s ready (LDS-only); prefetch stays in flight
  if (tid < 64) {
    float wv = w_s[tid];
#pragma unroll
    for (int m = 1; m < 64; m <<= 1) wv += __shfl_xor(wv, m, 64);
    if (tid == 0) stc_f(a.psump + sc4 * 64 + b, wv);
  }
  // ---- 4-way b-group flag sync (drains vmcnt: prefetch completes here) ----
  asm volatile("s_waitcnt vmcnt(0)" ::: "memory");
  __syncthreads();
  if (tid == 0) stc_u32(&a.bar[64 + (b << 2) + sc4], (unsigned)(t + 1));
  if (tid < 4) {
    while (__hip_atomic_load(&a.bar[64 + (b << 2) + tid], __ATOMIC_RELAXED,
                             __HIP_MEMORY_SCOPE_AGENT) < (unsigned)(t + 1))
      __builtin_amdgcn_s_sleep(1);
  }
  __syncthreads();
  // ---- A2: normalized context -> ctxR slot t%WCTX ----
  // Thread (w,lg,s0) holds d = w*32+lg*8+k (k=0..7), s = s0..s0+15.
  // Reduce over s0 via 16-lane shfl tree; writer lane&15==0 packs 8 consec d.
  float* wn = (float*)(dsm + SCR);  // reuse: 256 normalized weights
  float psinv = 1.f / (ldc_f(a.psump + b) + ldc_f(a.psump + 64 + b) +
                       ldc_f(a.psump + 128 + b) + ldc_f(a.psump + 192 + b));
  if (tid < 256) wn[tid] = ldc_f(a.wbuf + (size_t)b * Sn + tid) * psinv;
  __syncthreads();
  float wns[16];
#pragma unroll
  for (int j = 0; j < 16; ++j) wns[j] = wn[s0 + j];
  float part[8];
#pragma unroll
  for (int k = 0; k < 8; ++k) {
    unsigned ws4[4] = { er[k].x, er[k].y, er[k].z, er[k].w };
    float p = 0.f;
#pragma unroll
    for (int q = 0; q < 4; ++q) {
      floatx2 lo = dec2lo(ws4[q]), hi = dec2hi(ws4[q]);
      p += wns[q * 4] * lo[0] + wns[q * 4 + 1] * lo[1]
         + wns[q * 4 + 2] * hi[0] + wns[q * 4 + 3] * hi[1];
    }
    part[k] = p;
  }
#pragma unroll
  for (int m = 1; m < 16; m <<= 1) {
#pragma unroll
    for (int k = 0; k < 8; ++k) part[k] += __shfl_xor(part[k], m, 64);
  }
  if ((lane & 15) == 0) {
    union { unsigned long long u[2]; unsigned short s16[8]; } pkt;
#pragma unroll
    for (int k = 0; k < 8; ++k) pkt.s16[k] = f2bf(part[k]);
    unsigned long long* dst = (unsigned long long*)(
        a.ctxR + (size_t)(t % WCTX) * Bn * H2n + (size_t)b * H2n + sc4 * 512
        + w * 32 + lg * 8);
    stc_u64(dst, pkt.u[0]); stc_u64(dst + 1, pkt.u[1]);
  }
}

// Phase C, gate blocks (LDS-resident weights, R15-verified)
__device__ __forceinline__ void gate_c(const DA& a, char* dsm, int j0, int w,
                                       int lane, int tid, int t, int cur, int nxt) {
  float* scr = (float*)(dsm + SCR);  // [4 gate][64 b][8 j]
  for (int i = tid; i < 2048; i += NTHR) scr[i] = 0.f;
  __syncthreads();
  const int mt = w & 3, ks = w >> 2;
  const int lm = lane & 15, lk = lane >> 4;
  const int arow = mt * 16 + lm, jb = lm & 7;
  const unsigned short* ctxrow =
      a.ctxR + (size_t)(t % WCTX) * Bn * H2n + (size_t)arow * H2n + lk * 8;
  const unsigned short* hrow =
      a.hbR + (size_t)(t % WH) * Bn * Hn + (size_t)arow * Hn + lk * 8;
  const char* wb0 = dsm + GW + (size_t)((0 * 8 + jb) * 384) * 16;
  const char* wb1 = dsm + GW + (size_t)((1 * 8 + jb) * 384) * 16;
  const char* wb2 = dsm + GW + (size_t)((2 * 8 + jb) * 384) * 16;
  floatx4 ar = {0,0,0,0}, az = {0,0,0,0}, ain = {0,0,0,0}, ahn = {0,0,0,0};
#pragma unroll 4
  for (int kc = ks * 24; kc < ks * 24 + 24; ++kc) {
    short8v x = (kc < 64) ? ldf(ctxrow + kc * 32) : ldf(hrow + (kc - 64) * 32);
    const size_t slot = (size_t)((kc * 4 + lk) ^ jb) * 16;
    ar = MFMA(x, *(const short8v*)(wb0 + slot), ar);
    az = MFMA(x, *(const short8v*)(wb1 + slot), az);
    if (kc < 64) ain = MFMA(x, *(const short8v*)(wb2 + slot), ain);
    else         ahn = MFMA(x, *(const short8v*)(wb2 + slot), ahn);
  }
  if (lm < 8) {
#pragma unroll
    for (int r = 0; r < 4; ++r) {
      const int bb = mt * 16 + lk * 4 + r;
      atomicAdd(&scr[(0 * 64 + bb) * 8 + jb], ar[r]);
      atomicAdd(&scr[(1 * 64 + bb) * 8 + jb], az[r]);
      atomicAdd(&scr[(2 * 64 + bb) * 8 + jb], ain[r]);
      atomicAdd(&scr[(3 * 64 + bb) * 8 + jb], ahn[r]);
    }
  }
  __syncthreads();
  if (tid < 256) {
    const int bb = tid >> 2, jj = (tid & 3) * 2;
    float* gil = (float*)(dsm + GIL);
    float hn2[2];
#pragma unroll
    for (int u = 0; u < 2; ++u) {
      const int j = jj + u, jg = j0 + j;
      float grv = scr[(0 * 64 + bb) * 8 + j] + gil[(0 * 64 + bb) * 8 + j] + a.bhh[jg];
      float gzv = scr[(1 * 64 + bb) * 8 + j] + gil[(1 * 64 + bb) * 8 + j] + a.bhh[Hn + jg];
      float ginv = scr[(2 * 64 + bb) * 8 + j] + gil[(2 * 64 + bb) * 8 + j];
      float ghnv = scr[(3 * 64 + bb) * 8 + j] + a.bhh[2 * Hn + jg];
      float rr = sigm(grv), zz = sigm(gzv);
      float nn = tanh_f(ginv + rr * ghnv);
      float hold = a.hbuf[(size_t)cur * Bn * Hn + (size_t)bb * Hn + jg];
      float hnew = (1.f - zz) * nn + zz * hold;
      hn2[u] = hnew;
      a.hbuf[(size_t)nxt * Bn * Hn + (size_t)bb * Hn + jg] = hnew;
      a.out[((size_t)bb * Tn + t) * Hn + jg] = hnew;
      if (t == Tn - 1) a.out[(size_t)Bn * Tn * Hn + (size_t)bb * Hn + jg] = hnew;
    }
    unsigned hpack = (unsigned)f2bf(hn2[0]) | ((unsigned)f2bf(hn2[1]) << 16);
    stc_u32((unsigned*)(a.hbR + (size_t)((t + 1) % WH) * Bn * Hn +
                        (size_t)bb * Hn + j0 + jj), hpack);
  }
}

// Phase C, pre blocks (LDS-resident weights)
__device__ __forceinline__ void pre_c(const DA& a, char* dsm, int j0, int w,
                                      int lane, int tid, int t) {
  float* prep = (float*)(dsm + PREP);  // [64][8]
  for (int i = tid; i < 512; i += NTHR) prep[i] = 0.f;
  __syncthreads();
  const int mt = w & 3, ks = w >> 2;
  const int lm = lane & 15, lk = lane >> 4;
  const int arow = mt * 16 + lm, jb = lm & 7;
  const unsigned short* ctxrow =
      a.ctxR + (size_t)(t % WCTX) * Bn * H2n + (size_t)arow * H2n + lk * 8;
  const float* ep = a.emb + ((size_t)arow * Tn + t) * En + lk * 8;
  const char* we = dsm + PWe + (size_t)(jb * 64) * 16;
  const char* wc = dsm + PWc + (size_t)(jb * 256) * 16;
  floatx4 acc = {0,0,0,0};
#pragma unroll 4
  for (int kc = ks * 20; kc < ks * 20 + 20; ++kc) {
    if (kc < 16) {
      acc = MFMA(packf(ep + kc * 32),
                 *(const short8v*)(we + (size_t)((kc * 4 + lk) ^ jb) * 16), acc);
    } else {
      const int c = kc - 16;
      acc = MFMA(ldf(ctxrow + c * 32),
                 *(const short8v*)(wc + (size_t)((c * 4 + lk) ^ jb) * 16), acc);
    }
  }
  if (lm < 8) {
#pragma unroll
    for (int r = 0; r < 4; ++r)
      atomicAdd(&prep[(mt * 16 + lk * 4 + r) * 8 + jb], acc[r]);
  }
  __syncthreads();
}

// Phase D, pre blocks (LDS-resident weights)
__device__ __forceinline__ void pre_d(const DA& a, char* dsm, int j0, int w,
                                      int lane, int tid, int t, int hslot, int doPre) {
  float* scr = (float*)(dsm + SCR2);  // [2][64][8] : P then Q
  for (int i = tid; i < 1024; i += NTHR) scr[i] = 0.f;
  __syncthreads();
  const int mt = w & 3, part = w >> 2;
  const int lm = lane & 15, lk = lane >> 4;
  const int arow = mt * 16 + lm, jb = lm & 7;
  const unsigned short* hrow =
      a.hbR + (size_t)hslot * Bn * Hn + (size_t)arow * Hn + lk * 8;
  const int isQ = part >> 1;
  const char* wbase = dsm + (isQ ? PWq : PWh) + (size_t)(jb * 128) * 16;
  if (doPre || isQ) {
    floatx4 acc = {0,0,0,0};
    const int k0 = (part & 1) * 16;
#pragma unroll 4
    for (int kh = k0; kh < k0 + 16; ++kh)
      acc = MFMA(ldf(hrow + kh * 32),
                 *(const short8v*)(wbase + (size_t)((kh * 4 + lk) ^ jb) * 16), acc);
    if (lm < 8) {
#pragma unroll
      for (int r = 0; r < 4; ++r)
        atomicAdd(&scr[(isQ * 64 + mt * 16 + lk * 4 + r) * 8 + jb], acc[r]);
    }
  }
  __syncthreads();
  if (tid < 256) {
    const int bb = tid >> 2, jj = (tid & 3) * 2;
    float* prep = (float*)(dsm + PREP);
#pragma unroll
    for (int u = 0; u < 2; ++u) {
      const int j = jj + u, jg = j0 + j;
      if (doPre) {
        float pv = scr[(0 * 64 + bb) * 8 + j] + prep[bb * 8 + j];
        a.out[(size_t)Bn * Tn * Hn + (size_t)Bn * Hn + ((size_t)bb * Tn + t) * Hn + jg] = pv;
      }
      stc_f(a.qbuf + (size_t)bb * Hn + jg, scr[(1 * 64 + bb) * 8 + j]);
    }
  }
}

// Phase D, gate blocks
__device__ __forceinline__ void gi_compute(const DA& a, char* dsm, int j0, int w,
                                           int lane, int t1) {
  const int mt = w & 3, g = w >> 2;
  if (g >= 3) return;
  const int lm = lane & 15, lk = lane >> 4;
  const int arow = mt * 16 + lm;
  const unsigned short* wrow = a.Wih + (size_t)(g * Hn + j0 + (lm & 7)) * 2560 + lk * 8;
  const float* ep = a.emb + ((size_t)arow * Tn + t1) * En + lk * 8;
  floatx4 acc = {0,0,0,0};
#pragma unroll 4
  for (int kk = 0; kk < 16; ++kk)
    acc = MFMA(packf(ep + kk * 32), ldf(wrow + kk * 32), acc);
  if (lm < 8) {
    float* gil = (float*)(dsm + GIL);
    float bv = a.bih[g * Hn + j0 + lm];
#pragma unroll
    for (int r = 0; r < 4; ++r)
      gil[(g * 64 + mt * 16 + lk * 4 + r) * 8 + lm] = acc[r] + bv;
  }
}

// waves_per_eu(4,4): exactly 4 waves/EU -> no occupancy reward for <=64 VGPRs.
__global__ void __attribute__((amdgpu_flat_work_group_size(1024, 1024),
                               amdgpu_waves_per_eu(4, 4)))
dec_kernel(DA a) {
  extern __shared__ char dsm[];
  const int tid = threadIdx.x, bid = blockIdx.x;
  const int w = tid >> 6, lane = tid & 63;
  const bool isGate = bid < 128;
  const int j0 = (isGate ? bid : bid - 128) * 8;
  const int pb = bid >> 2, psc4 = bid & 3;  // phA partition (all blocks)

  // ---- load persistent weights into LDS (slot-XOR swizzled per j-row) ----
  if (isGate) {
    for (int idx = tid; idx < 9216; idx += NTHR) {
      int row = idx / 384, c = idx % 384;
      int g = row >> 3, j = row & 7;
      const unsigned short* src = (c < 256)
          ? a.Wih + (size_t)(g * Hn + j0 + j) * 2560 + 512 + c * 8
          : a.Whh + (size_t)(g * Hn + j0 + j) * Hn + (c - 256) * 8;
      *(uint4*)(dsm + (size_t)(row * 384 + (c ^ j)) * 16) = *(const uint4*)src;
    }
  } else {
    for (int idx = tid; idx < 4608; idx += NTHR) {
      const unsigned short* src; size_t dst;
      if (idx < 2048) {
        int j = idx >> 8, c = idx & 255;
        src = a.Wpre + (size_t)(j0 + j) * 3584 + 1536 + c * 8;
        dst = PWc + (size_t)(j * 256 + (c ^ j)) * 16;
      } else if (idx < 3072) {
        int i = idx - 2048, j = i >> 7, c = i & 127;
        src = a.Wpre + (size_t)(j0 + j) * 3584 + 512 + c * 8;
        dst = PWh + (size_t)(j * 128 + (c ^ j)) * 16;
      } else if (idx < 4096) {
        int i = idx - 3072, j = i >> 7, c = i & 127;
        src = a.Wq + (size_t)(j0 + j) * Hn + c * 8;
        dst = PWq + (size_t)(j * 128 + (c ^ j)) * 16;
      } else {
        int i = idx - 4096, j = i >> 6, c = i & 63;
        src = a.Wpre + (size_t)(j0 + j) * 3584 + c * 8;
        dst = PWe + (size_t)(j * 64 + (c ^ j)) * 16;
      }
      *(uint4*)(dsm + dst) = *(const uint4*)src;
    }
    // ---- stage this block's 64 KB fp8 pk slice into LDS (once) ----
    const unsigned char* ps = a.pk8 + ((size_t)pb * Sn + psc4 * 64) * 1024;
    for (int idx = tid; idx < 4096; idx += NTHR)
      *(uint4*)(dsm + PKL + (size_t)idx * 16) = *(const uint4*)(ps + (size_t)idx * 16);
  }
  __syncthreads();

  uint4 pkr8[4];
  unsigned bi = 1;
  // P0: gate blocks -> gi(0); pre blocks -> q(0) from h0 (hbR slot 0)
  if (isGate) gi_compute(a, dsm, j0, w, lane, 0);
  else pre_d(a, dsm, j0, w, lane, tid, 0, 0, 0);
  gbar_pk(a, a.bar, tid, bi++, 0, isGate, pb, psc4, w, lane, pkr8);

  for (int t = 0; t < Tn; ++t) {
    const int cur = t & 1, nxt = cur ^ 1;
    phA(a, dsm, bid, tid, w, lane, t, pkr8, isGate);  // internal 4-way sync
    gbar(a.bar, tid, bi++, 0);                // A->C: full grid (ctx for all b)
    if (isGate) {
      gate_c(a, dsm, j0, w, lane, tid, t, cur, nxt);
      gateC_signal(a.bar, tid);               // h(t+1) published; no wait
      if (t + 1 < Tn) gi_compute(a, dsm, j0, w, lane, t + 1);
    } else {
      pre_c(a, dsm, j0, w, lane, tid, t);
      gateC_wait(a.bar, tid, 128u * (unsigned)(t + 1));  // need h(t+1)
      pre_d(a, dsm, j0, w, lane, tid, t, (t + 1) % WH, 1);
    }
    // D->A: wait on the 128 pre producers (qbuf); gates prefetch pk8 in poll
    preD_wait_pk(a, a.bar, tid, 128u * (unsigned)(t + 1), (t & 7) == 7,
                 isGate, pb, psc4, w, lane, pkr8);
  }
}

// ---------- host launcher ----------
extern "C" void kernel_launch(void* const* d_in, const int* in_sizes, int n_in,
                              void* d_out, int out_size, void* d_ws, size_t ws_size,
                              hipStream_t stream) {
  (void)in_sizes; (void)n_in; (void)out_size; (void)ws_size;
  const float* emb = (const float*)d_in[0];
  const float* eh  = (const float*)d_in[1];
  const float* ef  = (const float*)d_in[2];
  const float* Wb  = (const float*)d_in[5];
  const float* bb  = (const float*)d_in[6];
  const float* Wk  = (const float*)d_in[7];
  const float* Wq  = (const float*)d_in[8];
  const float* v   = (const float*)d_in[9];
  const float* Wih = (const float*)d_in[10];
  const float* Whh = (const float*)d_in[11];
  const float* bih = (const float*)d_in[12];
  const float* bhh = (const float*)d_in[13];
  const float* Wpre= (const float*)d_in[14];
  float* out = (float*)d_out;

  // Compact layout: both steady-state streams (ehb8T, pk8) are fp8.
  char* wsb = (char*)d_ws;
  unsigned char*  ehb8 = (unsigned char*)(wsb + 0);             // 33,554,432 (fp8, TRANSPOSED [b][d][s])
  unsigned char*  pk8  = (unsigned char*)(wsb + 33554432);      // 16,777,216 (fp8)
  unsigned short* Wihb = (unsigned short*)(wsb + 50331648);     // 15,728,640
  unsigned short* Whhb = (unsigned short*)(wsb + 66060288);     //  6,291,456
  unsigned short* Wpreb= (unsigned short*)(wsb + 72351744);     //  7,340,032
  unsigned short* Wqb  = (unsigned short*)(wsb + 79691776);     //  2,097,152
  unsigned short* Wkb  = (unsigned short*)(wsb + 81788928);     //  4,194,304 (dead after pk_gemm)
  // rotated buffers overlay the Wkb region (written only after pk_gemm consumed it)
  unsigned short* ctxR = (unsigned short*)(wsb + 81788928);     // 10 x 262,144 = 2,621,440
  unsigned short* hbR  = (unsigned short*)(wsb + 84410368);     // 12 x 131,072 = 1,572,864 (ends 85,983,232)
  float* hbuf = (float*)(wsb + 85983232);                       //    524,288
  float* qbuf = (float*)(wsb + 86507520);                       //    262,144
  float* wbuf = (float*)(wsb + 86769664);                       //     65,536
  float* psump= (float*)(wsb + 86835200);                       //      4,096
  unsigned* bar = (unsigned*)(wsb + 86839296);                  //      4,096

  hipMemsetAsync(bar, 0, 4096, stream);
  cast8t_kernel<<<8192, 256, 0, stream>>>(eh, ehb8);
  cast_kernel<<<2048, 256, 0, stream>>>((const float4*)Wih, (uint2*)Wihb, 3 * Hn * 2560 / 4);
  cast_kernel<<<1024, 256, 0, stream>>>((const float4*)Whh, (uint2*)Whhb, 3 * Hn * Hn / 4);
  cast_kernel<<<1024, 256, 0, stream>>>((const float4*)Wpre, (uint2*)Wpreb, Hn * 3584 / 4);
  cast_kernel<<<512, 256, 0, stream>>>((const float4*)Wq, (uint2*)Wqb, Hn * Hn / 4);
  cast_kernel<<<512, 256, 0, stream>>>((const float4*)Wk, (uint2*)Wkb, Hn * H2n / 4);
  pk_gemm<<<4096, 256, 0, stream>>>(eh, Wkb, pk8);
  // bridge writes hbR slot 0 (inside the ex-Wkb region) -> must run AFTER pk_gemm
  bridge_kernel<<<256, 256, 0, stream>>>(ef, Wb, bb, hbuf, hbR);

  DA da;
  da.emb = emb; da.v = v; da.bih = bih; da.bhh = bhh;
  da.pk8 = pk8; da.ehb8 = ehb8;
  da.Wih = Wihb; da.Whh = Whhb; da.Wpre = Wpreb; da.Wq = Wqb;
  da.hbuf = hbuf; da.hbR = hbR; da.qbuf = qbuf; da.wbuf = wbuf; da.psump = psump;
  da.ctxR = ctxR; da.bar = bar; da.out = out;

  hipFuncSetAttribute(reinterpret_cast<const void*>(&dec_kernel),
                      hipFuncAttributeMaxDynamicSharedMemorySize, LDS_BYTES);
  void* kp[] = { (void*)&da };
  hipLaunchCooperativeKernel(reinterpret_cast<const void*>(&dec_kernel),
                             dim3(NBLK), dim3(NTHR), kp, LDS_BYTES, stream);
}

// Round 20
// 10582.943 us; speedup vs baseline: 1.4598x; 1.0536x over previous
//
#include <hip/hip_runtime.h>

#define Bn 64
#define Sn 256
#define Tn 128
#define Hn 1024
#define En 512
#define H2n 2048
#define NBLK 256
#define NTHR 1024

// rotation depths (reuse distance > fence period 8 + read window)
#define WCTX 10
#define WH 12

// LDS byte offsets (dynamic shared)
#define GW 0
#define PWc 0
#define PWh 32768
#define PWq 49152
#define PWe 65536
#define PREP 73728
#define SCR2 75776
#define PKL 81920          // pre blocks only: 64 KB fp8 pk slice
#define SCR 147456
#define GIL 155648
#define LDS_BYTES 161792

typedef __attribute__((ext_vector_type(8))) short short8v;
typedef __attribute__((ext_vector_type(4))) float floatx4;
typedef __attribute__((ext_vector_type(2))) float floatx2;

// HW OCP-fp8 decode if available (gfx940+/gfx950); else verified software path.
#if defined(__has_builtin)
#if __has_builtin(__builtin_amdgcn_cvt_pk_f32_fp8)
#define HW_FP8 1
#endif
#endif

__device__ __forceinline__ unsigned short f2bf(float f) {
  union { float f; unsigned u; } x; x.f = f;
  unsigned r = x.u + 0x7fffu + ((x.u >> 16) & 1u);
  return (unsigned short)(r >> 16);
}
__device__ __forceinline__ float bf2f(unsigned short u) {
  union { unsigned u; float f; } x; x.u = ((unsigned)u) << 16; return x.f;
}
__device__ __forceinline__ float sigm(float x) { return 1.f / (1.f + __expf(-x)); }
__device__ __forceinline__ float tanh_f(float x) {
  float e = __expf(2.f * x);
  return 1.f - 2.f / (e + 1.f);
}
__device__ __forceinline__ short8v ldf(const unsigned short* p) { return *(const short8v*)p; }
#define MFMA(a, b, c) __builtin_amdgcn_mfma_f32_16x16x32_bf16(a, b, c, 0, 0, 0)

// ---- fp8 e4m3fn FTZ codec (R11/R12/R15-verified in production) ----
// Encoder: RNE for normals, clamp 448, |x|<2^-7 -> 0, [2^-7,2^-6) -> min normal.
// Decoder (SW or HW) never sees subnormals from our encoder; HW OCP decode is
// bit-identical to dec1 on every emitted code (normals, +-0, 448 clamp).
__device__ __forceinline__ unsigned char f2fp8z(float f) {
  union { float f; unsigned u; } x; x.f = f;
  unsigned s = (x.u >> 24) & 0x80u;
  unsigned au = x.u & 0x7fffffffu;
  if (au >= 0x43e00000u) return (unsigned char)(s | 0x7Eu);   // clamp to 448
  if (au < 0x3c000000u) return (unsigned char)s;              // FTZ below 2^-7
  if (au < 0x3c800000u) return (unsigned char)(s | 0x08u);    // round to min normal
  unsigned r = au + 0x7ffffu + ((au >> 20) & 1u);             // RNE at bit 20
  unsigned e8 = ((r >> 23) & 0xffu) - 120u;
  unsigned m8 = (r >> 20) & 7u;
  return (unsigned char)(s | (e8 << 3) | m8);
}
__device__ __forceinline__ float dec1(unsigned b) {
  union { unsigned u; float f; } x;
  x.u = ((b & 0x80u) << 24) | ((b & 0x7fu) << 20);
  return x.f * 0x1p120f;
}
// decode bytes 0,1 / 2,3 of a packed dword to 2 floats
__device__ __forceinline__ floatx2 dec2lo(unsigned w) {
#ifdef HW_FP8
  return __builtin_amdgcn_cvt_pk_f32_fp8(w, false);
#else
  floatx2 r; r[0] = dec1(w & 0xffu); r[1] = dec1((w >> 8) & 0xffu); return r;
#endif
}
__device__ __forceinline__ floatx2 dec2hi(unsigned w) {
#ifdef HW_FP8
  return __builtin_amdgcn_cvt_pk_f32_fp8(w, true);
#else
  floatx2 r; r[0] = dec1((w >> 16) & 0xffu); r[1] = dec1(w >> 24); return r;
#endif
}
__device__ __forceinline__ void dec4f(unsigned w4, float wf, float* acc) {
  floatx2 lo = dec2lo(w4), hi = dec2hi(w4);
  acc[0] += wf * lo[0];
  acc[1] += wf * lo[1];
  acc[2] += wf * hi[0];
  acc[3] += wf * hi[1];
}

// ---- cross-block helpers ----
__device__ __forceinline__ float ldc_f(const float* p) {
  return __hip_atomic_load(p, __ATOMIC_RELAXED, __HIP_MEMORY_SCOPE_AGENT);
}
__device__ __forceinline__ void stc_f(float* p, float v) {
  __hip_atomic_store(p, v, __ATOMIC_RELAXED, __HIP_MEMORY_SCOPE_AGENT);
}
__device__ __forceinline__ void stc_u32(unsigned* p, unsigned v) {
  __hip_atomic_store(p, v, __ATOMIC_RELAXED, __HIP_MEMORY_SCOPE_AGENT);
}
__device__ __forceinline__ unsigned long long ldc_u64(const unsigned long long* p) {
  return __hip_atomic_load(p, __ATOMIC_RELAXED, __HIP_MEMORY_SCOPE_AGENT);
}
__device__ __forceinline__ void stc_u64(unsigned long long* p, unsigned long long v) {
  __hip_atomic_store(p, v, __ATOMIC_RELAXED, __HIP_MEMORY_SCOPE_AGENT);
}

// LDS-only barrier: drains lgkmcnt, NOT vmcnt. sched_barrier fences per the
// hoisting-hazard rule.
__device__ __forceinline__ void bar_lds() {
  __builtin_amdgcn_sched_barrier(0);
  asm volatile("s_waitcnt lgkmcnt(0)" ::: "memory");
  __builtin_amdgcn_s_barrier();
  __builtin_amdgcn_sched_barrier(0);
}

// pack 8 consecutive fp32 -> bf16 fragment
__device__ __forceinline__ short8v packf(const float* p) {
  float4 e0 = *(const float4*)p, e1 = *(const float4*)(p + 4);
  short8v x;
  x[0] = (short)f2bf(e0.x); x[1] = (short)f2bf(e0.y);
  x[2] = (short)f2bf(e0.z); x[3] = (short)f2bf(e0.w);
  x[4] = (short)f2bf(e1.x); x[5] = (short)f2bf(e1.y);
  x[6] = (short)f2bf(e1.z); x[7] = (short)f2bf(e1.w);
  return x;
}

// ---------- generic fp32 -> bf16 cast ----------
__global__ __launch_bounds__(256) void cast_kernel(const float4* __restrict__ src,
                                                   uint2* __restrict__ dst, int n4) {
  for (int i = blockIdx.x * blockDim.x + threadIdx.x; i < n4; i += gridDim.x * blockDim.x) {
    float4 v = src[i];
    uint2 p;
    p.x = (unsigned)f2bf(v.x) | ((unsigned)f2bf(v.y) << 16);
    p.y = (unsigned)f2bf(v.z) | ((unsigned)f2bf(v.w) << 16);
    dst[i] = p;
  }
}

// ---------- fp32 -> fp8 e4m3 FTZ cast (4 elems -> 1 dword) ----------
__global__ __launch_bounds__(256) void cast8_kernel(const float4* __restrict__ src,
                                                    unsigned* __restrict__ dst, int n4) {
  for (int i = blockIdx.x * blockDim.x + threadIdx.x; i < n4; i += gridDim.x * blockDim.x) {
    float4 v = src[i];
    unsigned p = (unsigned)f2fp8z(v.x) | ((unsigned)f2fp8z(v.y) << 8) |
                 ((unsigned)f2fp8z(v.z) << 16) | ((unsigned)f2fp8z(v.w) << 24);
    dst[i] = p;
  }
}

// ---------- bridge: h0 = tanh(ef @ Wb^T + bb) ----------
__global__ __launch_bounds__(256) void bridge_kernel(const float* __restrict__ ef,
                                                     const float* __restrict__ Wb,
                                                     const float* __restrict__ bb,
                                                     float* __restrict__ h0out,
                                                     unsigned short* __restrict__ hb0) {
  __shared__ float efs[H2n];
  const int b = blockIdx.x >> 2, jq = blockIdx.x & 3;
  const int j = jq * 256 + threadIdx.x;
  for (int i = threadIdx.x; i < H2n; i += 256) efs[i] = ef[(size_t)b * H2n + i];
  __syncthreads();
  const float* wr = Wb + (size_t)j * H2n;
  float acc = bb[j];
  for (int k = 0; k < H2n; k += 4) {
    float4 wv = *(const float4*)&wr[k];
    acc += efs[k] * wv.x + efs[k + 1] * wv.y + efs[k + 2] * wv.z + efs[k + 3] * wv.w;
  }
  float th = tanhf(acc);
  h0out[(size_t)b * Hn + j] = th;
  hb0[(size_t)b * Hn + j] = f2bf(th);
}

// ---------- proj_key MFMA GEMM: f32 A packed on the fly, fp8 output ----------
__global__ __launch_bounds__(256) void pk_gemm(const float* __restrict__ A,
                                               const unsigned short* __restrict__ Bw,
                                               unsigned char* __restrict__ pk8) {
  const int bid = blockIdx.x;  // 4096 = 256 mt x 16 nt
  const int mt = bid >> 4, nt = bid & 15;
  const int w = threadIdx.x >> 6, lane = threadIdx.x & 63;
  const int lm = lane & 15, lk = lane >> 4, ko = lk * 8;
  const float* arow = A + (size_t)(mt * 64 + w * 16 + lm) * 2048 + ko;
  const unsigned short* b0 = Bw + (size_t)(nt * 64 + lm) * 2048 + ko;
  const unsigned short* b1 = Bw + (size_t)(nt * 64 + 16 + lm) * 2048 + ko;
  const unsigned short* b2 = Bw + (size_t)(nt * 64 + 32 + lm) * 2048 + ko;
  const unsigned short* b3 = Bw + (size_t)(nt * 64 + 48 + lm) * 2048 + ko;
  floatx4 c0 = {0,0,0,0}, c1 = {0,0,0,0}, c2 = {0,0,0,0}, c3 = {0,0,0,0};
  for (int k = 0; k < 2048; k += 32) {
    short8v a = packf(arow + k);
    c0 = MFMA(a, ldf(b0 + k), c0);
    c1 = MFMA(a, ldf(b1 + k), c1);
    c2 = MFMA(a, ldf(b2 + k), c2);
    c3 = MFMA(a, ldf(b3 + k), c3);
  }
  const int m = mt * 64 + w * 16 + lk * 4;
  const int j = nt * 64 + lm;
#pragma unroll
  for (int r = 0; r < 4; ++r) {
    unsigned char* row = pk8 + (size_t)(m + r) * 1024 + j;
    row[0]  = f2fp8z(c0[r]);
    row[16] = f2fp8z(c1[r]);
    row[32] = f2fp8z(c2[r]);
    row[48] = f2fp8z(c3[r]);
  }
}

// ---------- decoder persistent kernel ----------
struct DA {
  const float* emb; const float* v; const float* bih; const float* bhh;
  const unsigned char* pk8; const unsigned char* ehb8;
  const unsigned short* Wih; const unsigned short* Whh;
  const unsigned short* Wpre; const unsigned short* Wq;
  float* hbuf; unsigned short* hbR; float* qbuf; float* wbuf; float* psump;
  unsigned short* ctxR; unsigned* bar; float* out;
};

// counter+generation full-grid barrier (R0-verified). Used at A->C.
__device__ __forceinline__ void gbar(unsigned* bar, int tid, unsigned idx, int inv) {
  asm volatile("s_waitcnt vmcnt(0)" ::: "memory");
  __syncthreads();
  if (tid == 0) {
    unsigned old = __hip_atomic_fetch_add(bar, 1u, __ATOMIC_RELAXED, __HIP_MEMORY_SCOPE_AGENT);
    if (old + 1u == (unsigned)NBLK * idx) {
      __hip_atomic_store(bar + 32, idx, __ATOMIC_RELAXED, __HIP_MEMORY_SCOPE_AGENT);
    } else {
      unsigned g;
      do {
        __builtin_amdgcn_s_sleep(2);
        g = __hip_atomic_load(bar + 32, __ATOMIC_RELAXED, __HIP_MEMORY_SCOPE_AGENT);
      } while (g < idx);
    }
  }
  __syncthreads();
  if (inv) __builtin_amdgcn_fence(__ATOMIC_ACQUIRE, "agent");
}

// Full-grid barrier with pk8 prefetch during the poll (P0 only; gates only).
__device__ __forceinline__ void gbar_pk(const DA& a, unsigned* bar, int tid, unsigned idx,
                                        int inv, int isGate, int b, int sc4, int w,
                                        int lane, uint4* pkr8) {
  asm volatile("s_waitcnt vmcnt(0)" ::: "memory");
  __syncthreads();
  __builtin_amdgcn_sched_barrier(0);
  if (isGate) {
#pragma unroll
    for (int i = 0; i < 4; ++i) {
      const unsigned char* prow =
          a.pk8 + ((size_t)b * Sn + sc4 * 64 + w * 4 + i) * 1024 + lane * 16;
      pkr8[i] = *(const uint4*)prow;
    }
  }
  __builtin_amdgcn_sched_barrier(0);
  if (tid == 0) {
    unsigned old = __hip_atomic_fetch_add(bar, 1u, __ATOMIC_RELAXED, __HIP_MEMORY_SCOPE_AGENT);
    if (old + 1u == (unsigned)NBLK * idx) {
      __hip_atomic_store(bar + 32, idx, __ATOMIC_RELAXED, __HIP_MEMORY_SCOPE_AGENT);
    } else {
      unsigned g;
      do {
        __builtin_amdgcn_s_sleep(2);
        g = __hip_atomic_load(bar + 32, __ATOMIC_RELAXED, __HIP_MEMORY_SCOPE_AGENT);
      } while (g < idx);
    }
  }
  __syncthreads();
  if (inv) __builtin_amdgcn_fence(__ATOMIC_ACQUIRE, "agent");
}

// C->D one-way flag: gate blocks drain gate_c stores and bump bar[512];
// they do NOT wait. Pre blocks poll for 128 gate arrivals before pre_d.
__device__ __forceinline__ void gateC_signal(unsigned* bar, int tid) {
  asm volatile("s_waitcnt vmcnt(0)" ::: "memory");
  __syncthreads();
  if (tid == 0)
    __hip_atomic_fetch_add(bar + 512, 1u, __ATOMIC_RELAXED, __HIP_MEMORY_SCOPE_AGENT);
}
__device__ __forceinline__ void gateC_wait(unsigned* bar, int tid, unsigned tgt) {
  __syncthreads();
  if (tid == 0) {
    while (__hip_atomic_load(bar + 512, __ATOMIC_RELAXED, __HIP_MEMORY_SCOPE_AGENT) < tgt)
      __builtin_amdgcn_s_sleep(1);
  }
  __syncthreads();
}

// D->A producer flag: the 128 pre blocks drain + bump bar[544]; ALL blocks
// wait for 128*(t+1); gate blocks issue next-phA's pk8 prefetch during the poll.
__device__ __forceinline__ void preD_wait_pk(const DA& a, unsigned* bar, int tid,
                                             unsigned tgt, int inv, int isGate,
                                             int b, int sc4, int w, int lane,
                                             uint4* pkr8) {
  if (!isGate) {
    asm volatile("s_waitcnt vmcnt(0)" ::: "memory");
    __syncthreads();
    if (tid == 0)
      __hip_atomic_fetch_add(bar + 544, 1u, __ATOMIC_RELAXED, __HIP_MEMORY_SCOPE_AGENT);
  } else {
    __syncthreads();
  }
  __builtin_amdgcn_sched_barrier(0);
  if (isGate) {
#pragma unroll
    for (int i = 0; i < 4; ++i) {
      const unsigned char* prow =
          a.pk8 + ((size_t)b * Sn + sc4 * 64 + w * 4 + i) * 1024 + lane * 16;
      pkr8[i] = *(const uint4*)prow;
    }
  }
  __builtin_amdgcn_sched_barrier(0);
  if (tid == 0) {
    while (__hip_atomic_load(bar + 544, __ATOMIC_RELAXED, __HIP_MEMORY_SCOPE_AGENT) < tgt)
      __builtin_amdgcn_s_sleep(1);
  }
  __syncthreads();
  if (inv) __builtin_amdgcn_fence(__ATOMIC_ACQUIRE, "agent");
}

// Phase A: energies (fp8 pk, HW decode) -> weights -> [4-way b-group flag
// sync] -> ctx quarter. ehb is fp8: all 8 A2 fragment loads (uint4 = 16 fp8
// each) prefetched right after energies, surviving the lgkm-only barrier until
// the flag-sync's vmcnt(0). A2 is HW-decode/FMA/shuffle -- no in-loop loads.
__device__ __forceinline__ void phA(const DA& a, char* dsm, int bid, int tid,
                                    int w, int lane, int t, uint4* pkr8, int isGate) {
  const int b = bid >> 2, sc4 = bid & 3;
  float* w_s = (float*)(dsm + SCR);          // 64 floats
  float* q_s = (float*)(dsm + SCR + 1024);   // 1024 floats
  if (tid < 256) {
    const unsigned long long* qp = (const unsigned long long*)(a.qbuf + (size_t)b * Hn) + tid * 2;
    unsigned long long u0 = ldc_u64(qp), u1 = ldc_u64(qp + 1);
    union { unsigned long long u; float f[2]; } x0, x1; x0.u = u0; x1.u = u1;
    q_s[tid * 4] = x0.f[0]; q_s[tid * 4 + 1] = x0.f[1];
    q_s[tid * 4 + 2] = x1.f[0]; q_s[tid * 4 + 3] = x1.f[1];
  }
  __syncthreads();
  if (!isGate) {
    // pk slice is LDS-resident (staged once at startup)
#pragma unroll
    for (int i = 0; i < 4; ++i)
      pkr8[i] = *(const uint4*)(dsm + PKL + (size_t)(w * 4 + i) * 1024 + lane * 16);
  }
  float qr[16], vr[16];
  const float* vp = a.v + lane * 16;
#pragma unroll
  for (int i = 0; i < 16; i += 4) {
    *(float4*)&qr[i] = *(const float4*)&q_s[lane * 16 + i];
    *(float4*)&vr[i] = *(const float4*)(vp + i);
  }
#pragma unroll
  for (int i = 0; i < 4; ++i) {
    float ep = 0.f;
    unsigned pw[4] = { pkr8[i].x, pkr8[i].y, pkr8[i].z, pkr8[i].w };
#pragma unroll
    for (int d = 0; d < 4; ++d) {
      floatx2 lo = dec2lo(pw[d]), hi = dec2hi(pw[d]);
      ep += vr[4 * d]     * tanh_f(qr[4 * d]     + lo[0]);
      ep += vr[4 * d + 1] * tanh_f(qr[4 * d + 1] + lo[1]);
      ep += vr[4 * d + 2] * tanh_f(qr[4 * d + 2] + hi[0]);
      ep += vr[4 * d + 3] * tanh_f(qr[4 * d + 3] + hi[1]);
    }
#pragma unroll
    for (int m = 1; m < 64; m <<= 1) ep += __shfl_xor(ep, m, 64);
    if (lane == 0) {
      float wv = __expf(ep - 20.f);  // |e| <= sum|v| ~ 16.5: fixed shift safe
      w_s[w * 4 + i] = wv;
      stc_f(a.wbuf + (size_t)b * Sn + sc4 * 64 + w * 4 + i, wv);
    }
  }
  // ---- A2 ehb8 prefetch: all 8 uint4 fragments (t-invariant addresses) ----
  const int ls = lane >> 1, ldcx = lane & 1;
  const int dchunk = w * 2 + ldcx;  // 0..31 (16 fp8 each) within the sc4 quarter
  const unsigned char* ebase = a.ehb8 + (size_t)b * Sn * H2n + sc4 * 512 + dchunk * 16;
  uint4 er[8];
#pragma unroll
  for (int k = 0; k < 8; ++k)
    er[k] = *(const uint4*)(ebase + (size_t)(ls + k * 32) * H2n);
  bar_lds();  // w_s ready (LDS-only); prefetch stays in flight
  if (tid < 64) {
    float wv = w_s[tid];
#pragma unroll
    for (int m = 1; m < 64; m <<= 1) wv += __shfl_xor(wv, m, 64);
    if (tid == 0) stc_f(a.psump + sc4 * 64 + b, wv);
  }
  // ---- 4-way b-group flag sync (drains vmcnt: prefetch completes here) ----
  asm volatile("s_waitcnt vmcnt(0)" ::: "memory");
  __syncthreads();
  if (tid == 0) stc_u32(&a.bar[64 + (b << 2) + sc4], (unsigned)(t + 1));
  if (tid < 4) {
    while (__hip_atomic_load(&a.bar[64 + (b << 2) + tid], __ATOMIC_RELAXED,
                             __HIP_MEMORY_SCOPE_AGENT) < (unsigned)(t + 1))
      __builtin_amdgcn_s_sleep(1);
  }
  __syncthreads();
  // ---- A2: normalized context -> ctxR slot t%WCTX (HW decode+FMA+shuffle) ----
  float* wn = (float*)(dsm + SCR);  // reuse: 256 normalized weights
  float psinv = 1.f / (ldc_f(a.psump + b) + ldc_f(a.psump + 64 + b) +
                       ldc_f(a.psump + 128 + b) + ldc_f(a.psump + 192 + b));
  if (tid < 256) wn[tid] = ldc_f(a.wbuf + (size_t)b * Sn + tid) * psinv;
  __syncthreads();
  float acc[16] = {};
#pragma unroll
  for (int k = 0; k < 8; ++k) {
    float wf = wn[ls + k * 32];
    dec4f(er[k].x, wf, acc);
    dec4f(er[k].y, wf, acc + 4);
    dec4f(er[k].z, wf, acc + 8);
    dec4f(er[k].w, wf, acc + 12);
  }
#pragma unroll
  for (int m = 2; m < 64; m <<= 1) {
#pragma unroll
    for (int e2 = 0; e2 < 16; ++e2) acc[e2] += __shfl_xor(acc[e2], m, 64);
  }
  if (ls == 0) {
    union { unsigned long long u[4]; unsigned short s[16]; } p;
#pragma unroll
    for (int e2 = 0; e2 < 16; ++e2) p.s[e2] = f2bf(acc[e2]);
    unsigned long long* dst = (unsigned long long*)(
        a.ctxR + (size_t)(t % WCTX) * Bn * H2n + (size_t)b * H2n + sc4 * 512 + dchunk * 16);
    stc_u64(dst, p.u[0]); stc_u64(dst + 1, p.u[1]);
    stc_u64(dst + 2, p.u[2]); stc_u64(dst + 3, p.u[3]);
  }
}

// Phase C, gate blocks
__device__ __forceinline__ void gate_c(const DA& a, char* dsm, int j0, int w,
                                       int lane, int tid, int t, int cur, int nxt) {
  float* scr = (float*)(dsm + SCR);  // [4 gate][64 b][8 j]
  for (int i = tid; i < 2048; i += NTHR) scr[i] = 0.f;
  __syncthreads();
  const int mt = w & 3, ks = w >> 2;
  const int lm = lane & 15, lk = lane >> 4;
  const int arow = mt * 16 + lm, jb = lm & 7;
  const unsigned short* ctxrow =
      a.ctxR + (size_t)(t % WCTX) * Bn * H2n + (size_t)arow * H2n + lk * 8;
  const unsigned short* hrow =
      a.hbR + (size_t)(t % WH) * Bn * Hn + (size_t)arow * Hn + lk * 8;
  const char* wb0 = dsm + GW + (size_t)((0 * 8 + jb) * 384) * 16;
  const char* wb1 = dsm + GW + (size_t)((1 * 8 + jb) * 384) * 16;
  const char* wb2 = dsm + GW + (size_t)((2 * 8 + jb) * 384) * 16;
  floatx4 ar = {0,0,0,0}, az = {0,0,0,0}, ain = {0,0,0,0}, ahn = {0,0,0,0};
#pragma unroll 4
  for (int kc = ks * 24; kc < ks * 24 + 24; ++kc) {
    short8v x = (kc < 64) ? ldf(ctxrow + kc * 32) : ldf(hrow + (kc - 64) * 32);
    const size_t slot = (size_t)((kc * 4 + lk) ^ jb) * 16;
    ar = MFMA(x, *(const short8v*)(wb0 + slot), ar);
    az = MFMA(x, *(const short8v*)(wb1 + slot), az);
    if (kc < 64) ain = MFMA(x, *(const short8v*)(wb2 + slot), ain);
    else         ahn = MFMA(x, *(const short8v*)(wb2 + slot), ahn);
  }
  if (lm < 8) {
#pragma unroll
    for (int r = 0; r < 4; ++r) {
      const int bb = mt * 16 + lk * 4 + r;
      atomicAdd(&scr[(0 * 64 + bb) * 8 + jb], ar[r]);
      atomicAdd(&scr[(1 * 64 + bb) * 8 + jb], az[r]);
      atomicAdd(&scr[(2 * 64 + bb) * 8 + jb], ain[r]);
      atomicAdd(&scr[(3 * 64 + bb) * 8 + jb], ahn[r]);
    }
  }
  __syncthreads();
  if (tid < 256) {
    const int bb = tid >> 2, jj = (tid & 3) * 2;
    float* gil = (float*)(dsm + GIL);
    float hn2[2];
#pragma unroll
    for (int u = 0; u < 2; ++u) {
      const int j = jj + u, jg = j0 + j;
      float grv = scr[(0 * 64 + bb) * 8 + j] + gil[(0 * 64 + bb) * 8 + j] + a.bhh[jg];
      float gzv = scr[(1 * 64 + bb) * 8 + j] + gil[(1 * 64 + bb) * 8 + j] + a.bhh[Hn + jg];
      float ginv = scr[(2 * 64 + bb) * 8 + j] + gil[(2 * 64 + bb) * 8 + j];
      float ghnv = scr[(3 * 64 + bb) * 8 + j] + a.bhh[2 * Hn + jg];
      float rr = sigm(grv), zz = sigm(gzv);
      float nn = tanh_f(ginv + rr * ghnv);
      float hold = a.hbuf[(size_t)cur * Bn * Hn + (size_t)bb * Hn + jg];
      float hnew = (1.f - zz) * nn + zz * hold;
      hn2[u] = hnew;
      a.hbuf[(size_t)nxt * Bn * Hn + (size_t)bb * Hn + jg] = hnew;
      a.out[((size_t)bb * Tn + t) * Hn + jg] = hnew;
      if (t == Tn - 1) a.out[(size_t)Bn * Tn * Hn + (size_t)bb * Hn + jg] = hnew;
    }
    unsigned hpack = (unsigned)f2bf(hn2[0]) | ((unsigned)f2bf(hn2[1]) << 16);
    stc_u32((unsigned*)(a.hbR + (size_t)((t + 1) % WH) * Bn * Hn +
                        (size_t)bb * Hn + j0 + jj), hpack);
  }
}

// Phase C, pre blocks
__device__ __forceinline__ void pre_c(const DA& a, char* dsm, int j0, int w,
                                      int lane, int tid, int t) {
  float* prep = (float*)(dsm + PREP);  // [64][8]
  for (int i = tid; i < 512; i += NTHR) prep[i] = 0.f;
  __syncthreads();
  const int mt = w & 3, ks = w >> 2;
  const int lm = lane & 15, lk = lane >> 4;
  const int arow = mt * 16 + lm, jb = lm & 7;
  const unsigned short* ctxrow =
      a.ctxR + (size_t)(t % WCTX) * Bn * H2n + (size_t)arow * H2n + lk * 8;
  const float* ep = a.emb + ((size_t)arow * Tn + t) * En + lk * 8;
  const char* we = dsm + PWe + (size_t)(jb * 64) * 16;
  const char* wc = dsm + PWc + (size_t)(jb * 256) * 16;
  floatx4 acc = {0,0,0,0};
#pragma unroll 4
  for (int kc = ks * 20; kc < ks * 20 + 20; ++kc) {
    if (kc < 16) {
      acc = MFMA(packf(ep + kc * 32),
                 *(const short8v*)(we + (size_t)((kc * 4 + lk) ^ jb) * 16), acc);
    } else {
      const int c = kc - 16;
      acc = MFMA(ldf(ctxrow + c * 32),
                 *(const short8v*)(wc + (size_t)((c * 4 + lk) ^ jb) * 16), acc);
    }
  }
  if (lm < 8) {
#pragma unroll
    for (int r = 0; r < 4; ++r)
      atomicAdd(&prep[(mt * 16 + lk * 4 + r) * 8 + jb], acc[r]);
  }
  __syncthreads();
}

// Phase D, pre blocks
__device__ __forceinline__ void pre_d(const DA& a, char* dsm, int j0, int w,
                                      int lane, int tid, int t, int hslot, int doPre) {
  float* scr = (float*)(dsm + SCR2);  // [2][64][8] : P then Q
  for (int i = tid; i < 1024; i += NTHR) scr[i] = 0.f;
  __syncthreads();
  const int mt = w & 3, part = w >> 2;
  const int lm = lane & 15, lk = lane >> 4;
  const int arow = mt * 16 + lm, jb = lm & 7;
  const unsigned short* hrow =
      a.hbR + (size_t)hslot * Bn * Hn + (size_t)arow * Hn + lk * 8;
  const int isQ = part >> 1;
  const char* wbase = dsm + (isQ ? PWq : PWh) + (size_t)(jb * 128) * 16;
  if (doPre || isQ) {
    floatx4 acc = {0,0,0,0};
    const int k0 = (part & 1) * 16;
#pragma unroll 4
    for (int kh = k0; kh < k0 + 16; ++kh)
      acc = MFMA(ldf(hrow + kh * 32),
                 *(const short8v*)(wbase + (size_t)((kh * 4 + lk) ^ jb) * 16), acc);
    if (lm < 8) {
#pragma unroll
      for (int r = 0; r < 4; ++r)
        atomicAdd(&scr[(isQ * 64 + mt * 16 + lk * 4 + r) * 8 + jb], acc[r]);
    }
  }
  __syncthreads();
  if (tid < 256) {
    const int bb = tid >> 2, jj = (tid & 3) * 2;
    float* prep = (float*)(dsm + PREP);
#pragma unroll
    for (int u = 0; u < 2; ++u) {
      const int j = jj + u, jg = j0 + j;
      if (doPre) {
        float pv = scr[(0 * 64 + bb) * 8 + j] + prep[bb * 8 + j];
        a.out[(size_t)Bn * Tn * Hn + (size_t)Bn * Hn + ((size_t)bb * Tn + t) * Hn + jg] = pv;
      }
      stc_f(a.qbuf + (size_t)bb * Hn + jg, scr[(1 * 64 + bb) * 8 + j]);
    }
  }
}

// Phase D, gate blocks
__device__ __forceinline__ void gi_compute(const DA& a, char* dsm, int j0, int w,
                                           int lane, int t1) {
  const int mt = w & 3, g = w >> 2;
  if (g >= 3) return;
  const int lm = lane & 15, lk = lane >> 4;
  const int arow = mt * 16 + lm;
  const unsigned short* wrow = a.Wih + (size_t)(g * Hn + j0 + (lm & 7)) * 2560 + lk * 8;
  const float* ep = a.emb + ((size_t)arow * Tn + t1) * En + lk * 8;
  floatx4 acc = {0,0,0,0};
#pragma unroll 4
  for (int kk = 0; kk < 16; ++kk)
    acc = MFMA(packf(ep + kk * 32), ldf(wrow + kk * 32), acc);
  if (lm < 8) {
    float* gil = (float*)(dsm + GIL);
    float bv = a.bih[g * Hn + j0 + lm];
#pragma unroll
    for (int r = 0; r < 4; ++r)
      gil[(g * 64 + mt * 16 + lk * 4 + r) * 8 + lm] = acc[r] + bv;
  }
}

// waves_per_eu(4,4): exactly 4 waves/EU -> no occupancy reward for <=64 VGPRs.
__global__ void __attribute__((amdgpu_flat_work_group_size(1024, 1024),
                               amdgpu_waves_per_eu(4, 4)))
dec_kernel(DA a) {
  extern __shared__ char dsm[];
  const int tid = threadIdx.x, bid = blockIdx.x;
  const int w = tid >> 6, lane = tid & 63;
  const bool isGate = bid < 128;
  const int j0 = (isGate ? bid : bid - 128) * 8;
  const int pb = bid >> 2, psc4 = bid & 3;  // phA partition (all blocks)

  // ---- load persistent weights into LDS (slot-XOR swizzled per j-row) ----
  if (isGate) {
    for (int idx = tid; idx < 9216; idx += NTHR) {
      int row = idx / 384, c = idx % 384;
      int g = row >> 3, j = row & 7;
      const unsigned short* src = (c < 256)
          ? a.Wih + (size_t)(g * Hn + j0 + j) * 2560 + 512 + c * 8
          : a.Whh + (size_t)(g * Hn + j0 + j) * Hn + (c - 256) * 8;
      *(uint4*)(dsm + (size_t)(row * 384 + (c ^ j)) * 16) = *(const uint4*)src;
    }
  } else {
    for (int idx = tid; idx < 4608; idx += NTHR) {
      const unsigned short* src; size_t dst;
      if (idx < 2048) {
        int j = idx >> 8, c = idx & 255;
        src = a.Wpre + (size_t)(j0 + j) * 3584 + 1536 + c * 8;
        dst = PWc + (size_t)(j * 256 + (c ^ j)) * 16;
      } else if (idx < 3072) {
        int i = idx - 2048, j = i >> 7, c = i & 127;
        src = a.Wpre + (size_t)(j0 + j) * 3584 + 512 + c * 8;
        dst = PWh + (size_t)(j * 128 + (c ^ j)) * 16;
      } else if (idx < 4096) {
        int i = idx - 3072, j = i >> 7, c = i & 127;
        src = a.Wq + (size_t)(j0 + j) * Hn + c * 8;
        dst = PWq + (size_t)(j * 128 + (c ^ j)) * 16;
      } else {
        int i = idx - 4096, j = i >> 6, c = i & 63;
        src = a.Wpre + (size_t)(j0 + j) * 3584 + c * 8;
        dst = PWe + (size_t)(j * 64 + (c ^ j)) * 16;
      }
      *(uint4*)(dsm + dst) = *(const uint4*)src;
    }
    // ---- stage this block's 64 KB fp8 pk slice into LDS (once) ----
    const unsigned char* ps = a.pk8 + ((size_t)pb * Sn + psc4 * 64) * 1024;
    for (int idx = tid; idx < 4096; idx += NTHR)
      *(uint4*)(dsm + PKL + (size_t)idx * 16) = *(const uint4*)(ps + (size_t)idx * 16);
  }
  __syncthreads();

  uint4 pkr8[4];
  unsigned bi = 1;
  // P0: gate blocks -> gi(0); pre blocks -> q(0) from h0 (hbR slot 0)
  if (isGate) gi_compute(a, dsm, j0, w, lane, 0);
  else pre_d(a, dsm, j0, w, lane, tid, 0, 0, 0);
  gbar_pk(a, a.bar, tid, bi++, 0, isGate, pb, psc4, w, lane, pkr8);

  for (int t = 0; t < Tn; ++t) {
    const int cur = t & 1, nxt = cur ^ 1;
    phA(a, dsm, bid, tid, w, lane, t, pkr8, isGate);  // internal 4-way sync
    gbar(a.bar, tid, bi++, 0);                // A->C: full grid (ctx for all b)
    if (isGate) {
      gate_c(a, dsm, j0, w, lane, tid, t, cur, nxt);
      gateC_signal(a.bar, tid);               // h(t+1) published; no wait
      if (t + 1 < Tn) gi_compute(a, dsm, j0, w, lane, t + 1);
    } else {
      pre_c(a, dsm, j0, w, lane, tid, t);
      gateC_wait(a.bar, tid, 128u * (unsigned)(t + 1));  // need h(t+1)
      pre_d(a, dsm, j0, w, lane, tid, t, (t + 1) % WH, 1);
    }
    // D->A: wait on the 128 pre producers (qbuf); gates prefetch pk8 in poll
    preD_wait_pk(a, a.bar, tid, 128u * (unsigned)(t + 1), (t & 7) == 7,
                 isGate, pb, psc4, w, lane, pkr8);
  }
}

// ---------- host launcher ----------
extern "C" void kernel_launch(void* const* d_in, const int* in_sizes, int n_in,
                              void* d_out, int out_size, void* d_ws, size_t ws_size,
                              hipStream_t stream) {
  (void)in_sizes; (void)n_in; (void)out_size; (void)ws_size;
  const float* emb = (const float*)d_in[0];
  const float* eh  = (const float*)d_in[1];
  const float* ef  = (const float*)d_in[2];
  const float* Wb  = (const float*)d_in[5];
  const float* bb  = (const float*)d_in[6];
  const float* Wk  = (const float*)d_in[7];
  const float* Wq  = (const float*)d_in[8];
  const float* v   = (const float*)d_in[9];
  const float* Wih = (const float*)d_in[10];
  const float* Whh = (const float*)d_in[11];
  const float* bih = (const float*)d_in[12];
  const float* bhh = (const float*)d_in[13];
  const float* Wpre= (const float*)d_in[14];
  float* out = (float*)d_out;

  // Compact layout: both steady-state streams (ehb, pk) are fp8.
  char* wsb = (char*)d_ws;
  unsigned char*  ehb8 = (unsigned char*)(wsb + 0);             // 33,554,432 (fp8)
  unsigned char*  pk8  = (unsigned char*)(wsb + 33554432);      // 16,777,216 (fp8)
  unsigned short* Wihb = (unsigned short*)(wsb + 50331648);     // 15,728,640
  unsigned short* Whhb = (unsigned short*)(wsb + 66060288);     //  6,291,456
  unsigned short* Wpreb= (unsigned short*)(wsb + 72351744);     //  7,340,032
  unsigned short* Wqb  = (unsigned short*)(wsb + 79691776);     //  2,097,152
  unsigned short* Wkb  = (unsigned short*)(wsb + 81788928);     //  4,194,304 (dead after pk_gemm)
  // rotated buffers overlay the Wkb region (written only after pk_gemm consumed it)
  unsigned short* ctxR = (unsigned short*)(wsb + 81788928);     // 10 x 262,144 = 2,621,440
  unsigned short* hbR  = (unsigned short*)(wsb + 84410368);     // 12 x 131,072 = 1,572,864 (ends 85,983,232)
  float* hbuf = (float*)(wsb + 85983232);                       //    524,288
  float* qbuf = (float*)(wsb + 86507520);                       //    262,144
  float* wbuf = (float*)(wsb + 86769664);                       //     65,536
  float* psump= (float*)(wsb + 86835200);                       //      4,096
  unsigned* bar = (unsigned*)(wsb + 86839296);                  //      4,096

  hipMemsetAsync(bar, 0, 4096, stream);
  cast8_kernel<<<2048, 256, 0, stream>>>((const float4*)eh, (unsigned*)ehb8,
                                         Bn * Sn * H2n / 4);
  cast_kernel<<<2048, 256, 0, stream>>>((const float4*)Wih, (uint2*)Wihb, 3 * Hn * 2560 / 4);
  cast_kernel<<<1024, 256, 0, stream>>>((const float4*)Whh, (uint2*)Whhb, 3 * Hn * Hn / 4);
  cast_kernel<<<1024, 256, 0, stream>>>((const float4*)Wpre, (uint2*)Wpreb, Hn * 3584 / 4);
  cast_kernel<<<512, 256, 0, stream>>>((const float4*)Wq, (uint2*)Wqb, Hn * Hn / 4);
  cast_kernel<<<512, 256, 0, stream>>>((const float4*)Wk, (uint2*)Wkb, Hn * H2n / 4);
  pk_gemm<<<4096, 256, 0, stream>>>(eh, Wkb, pk8);
  // bridge writes hbR slot 0 (inside the ex-Wkb region) -> must run AFTER pk_gemm
  bridge_kernel<<<256, 256, 0, stream>>>(ef, Wb, bb, hbuf, hbR);

  DA da;
  da.emb = emb; da.v = v; da.bih = bih; da.bhh = bhh;
  da.pk8 = pk8; da.ehb8 = ehb8;
  da.Wih = Wihb; da.Whh = Whhb; da.Wpre = Wpreb; da.Wq = Wqb;
  da.hbuf = hbuf; da.hbR = hbR; da.qbuf = qbuf; da.wbuf = wbuf; da.psump = psump;
  da.ctxR = ctxR; da.bar = bar; da.out = out;

  hipFuncSetAttribute(reinterpret_cast<const void*>(&dec_kernel),
                      hipFuncAttributeMaxDynamicSharedMemorySize, LDS_BYTES);
  void* kp[] = { (void*)&da };
  hipLaunchCooperativeKernel(reinterpret_cast<const void*>(&dec_kernel),
                             dim3(NBLK), dim3(NTHR), kp, LDS_BYTES, stream);
}